// Round 13
// baseline (402.840 us; speedup 1.0000x reference)
//
#include <hip/hip_runtime.h>
#include <hip/hip_bf16.h>
#include <math.h>

// ---------------------------------------------------------------------------
// GATv2 3-layer GNN. CSR-by-dst padded to 4-edge batches (self-loop folded
// in); f16 MFMA GEMMs; BN/ReLU/residual fused into attention.
// R10/R11 measured: 397us best. attn4_bn 67.4us (VALU 60, mem 45, occ 66 —
// nothing saturated => tail/latency component). R11: (a) attn blocks 256->128
// threads (2 waves/block): halves per-block straggler skew, finer retirement;
// (b) fold log2e into wt, use exp2f (saves the v_mul inside __expf);
// (c) scatter ILP 4->8 edges/thread (mechanism validated in R10).
// R12: fix compile — __exp2f is not a HIP intrinsic (glibc macro collision);
// use exp2f (lowers to a single v_exp_f32 on gfx950).
// ---------------------------------------------------------------------------

using h16     = _Float16;
using half2v  = __attribute__((ext_vector_type(2))) h16;
using half4v  = __attribute__((ext_vector_type(4))) h16;
using half8   = __attribute__((ext_vector_type(8))) h16;
using floatx2 = __attribute__((ext_vector_type(2))) float;
using floatx4 = __attribute__((ext_vector_type(4))) float;

__device__ __forceinline__ float lrelu(float x) { return x > 0.f ? x : 0.2f * x; }

__device__ __forceinline__ half2v shfl_xor_h2(half2v v, int mask) {
    float f = __builtin_bit_cast(float, v);
    f = __shfl_xor(f, mask, 64);
    return __builtin_bit_cast(half2v, f);
}

// ---------------- CSR build ----------------
// padded row length = ceil((deg+1)/4)*4  (self-loop + pads)
__global__ __launch_bounds__(256) void scan_blk(const int* __restrict__ deg,
                                                int* __restrict__ rowstart,
                                                int* __restrict__ bsum, int N) {
    int t = blockIdx.x * 256 + threadIdx.x;
    int lane = threadIdx.x & 63, wid = threadIdx.x >> 6;
    int v = (t < N) ? ((deg[t] + 4) & ~3) : 0;
    int x = v;
#pragma unroll
    for (int off = 1; off < 64; off <<= 1) {
        int y = __shfl_up(x, off, 64);
        if (lane >= off) x += y;
    }
    __shared__ int wsum[4];
    if (lane == 63) wsum[wid] = x;
    __syncthreads();
    int add = 0;
#pragma unroll
    for (int w = 0; w < 4; ++w) if (w < wid) add += wsum[w];
    int incl = x + add;
    if (t < N) rowstart[t] = incl - v;
    if (threadIdx.x == 255) bsum[blockIdx.x] = incl;
}

__global__ __launch_bounds__(256) void scan_off(int* __restrict__ bsum, int NB) {
    int t = threadIdx.x;
    int lane = t & 63, wid = t >> 6;
    int v = (t < NB) ? bsum[t] : 0;
    int x = v;
#pragma unroll
    for (int off = 1; off < 64; off <<= 1) {
        int y = __shfl_up(x, off, 64);
        if (lane >= off) x += y;
    }
    __shared__ int wsum[4];
    if (lane == 63) wsum[wid] = x;
    __syncthreads();
    int add = 0;
#pragma unroll
    for (int w = 0; w < 4; ++w) if (w < wid) add += wsum[w];
    if (t < NB) bsum[t] = x + add - v;
}

__global__ void add_off(const int* __restrict__ bsum, const int* __restrict__ deg,
                        int* __restrict__ rowstart, int* __restrict__ cursor,
                        int* __restrict__ csr_src, int N) {
    int t = blockIdx.x * 256 + threadIdx.x;
    if (t >= N) return;
    int r = rowstart[t] + bsum[blockIdx.x];
    rowstart[t] = r;
    cursor[t] = r;
    int dg = deg[t];
    int npad = (dg + 4) & ~3;
    for (int k = dg; k < npad; ++k) csr_src[r + k] = t;
}

// ------- weight packing + x conversion + dst histogram (one launch) -------
__device__ __forceinline__ void pack_one(const float* __restrict__ W,
                                         h16* __restrict__ Wp,
                                         int t, int K, int NC) {
    int j = t & 7;
    int l = (t >> 3) & 63;
    int rest = t >> 9;
    int NT = NC >> 4;
    int nt = rest % NT;
    int kc = rest / NT;
    int row = kc * 32 + (l >> 4) * 8 + j;
    int col = nt * 16 + (l & 15);
    Wp[t] = (h16)W[(size_t)row * NC + col];
}

__global__ void pack_all(const float* __restrict__ W_in,
                         const float* __restrict__ Wl0, const float* __restrict__ Wr0,
                         const float* __restrict__ Wl1, const float* __restrict__ Wr1,
                         h16* __restrict__ P_in,
                         h16* __restrict__ P_l0, h16* __restrict__ P_r0,
                         h16* __restrict__ P_l1, h16* __restrict__ P_r1,
                         const float4* __restrict__ x, half4v* __restrict__ xh, int n4,
                         const int* __restrict__ ei, int E, int* __restrict__ deg) {
    int t = blockIdx.x * blockDim.x + threadIdx.x;
    if (t < 8192)        pack_one(W_in, P_in, t, 128, 64);
    else if (t < 24576)  pack_one(Wl0, P_l0, t - 8192, 64, 256);
    else if (t < 40960)  pack_one(Wr0, P_r0, t - 24576, 64, 256);
    else if (t < 106496) pack_one(Wl1, P_l1, t - 40960, 256, 256);
    else if (t < 172032) pack_one(Wr1, P_r1, t - 106496, 256, 256);
    else if (t < 172032 + n4) {
        int u = t - 172032;
        float4 v = x[u];
        half4v o = { (h16)v.x, (h16)v.y, (h16)v.z, (h16)v.w };
        xh[u] = o;
    } else {
        int u = t - 172032 - n4;
        if (u < E) atomicAdd(&deg[ei[E + u]], 1);   // no-return atomic: throughput-ok
    }
}

// --------- MFMA GEMM body, double-buffered LDS staging of W ----------------
template<int KC, int NT, bool RELU>
__device__ __forceinline__ void gemm_body(const h16* __restrict__ Xh,
                                          const h16* __restrict__ Wp,
                                          const float* __restrict__ bias,
                                          h16* __restrict__ outp, int M, int bx) {
    constexpr int K = KC * 32;
    constexpr int ldo = NT * 16;
    constexpr int CHUNK8 = NT * 64;
    constexpr int PER_THR = CHUNK8 / 256;
    __shared__ half8 wbuf[2][CHUNK8];

    const half8* WG = (const half8*)Wp;
    const int tid = threadIdx.x;
    const int wid = tid >> 6, lane = tid & 63;
    const int quad = lane >> 4, li = lane & 15;
    const int r0 = bx * 64 + wid * 16;
    int arow = r0 + li; if (arow >= M) arow = M - 1;
    const half8* A8 = (const half8*)Xh + (size_t)arow * (K / 8) + quad;

    floatx4 acc[NT];
#pragma unroll
    for (int t = 0; t < NT; ++t) acc[t] = (floatx4){0.f, 0.f, 0.f, 0.f};

    half8 st[PER_THR];
#pragma unroll
    for (int i = 0; i < PER_THR; ++i) st[i] = WG[i * 256 + tid];
#pragma unroll
    for (int i = 0; i < PER_THR; ++i) wbuf[0][i * 256 + tid] = st[i];
    __syncthreads();

#pragma unroll
    for (int kc = 0; kc < KC; ++kc) {
        int cur = kc & 1;
        if (kc + 1 < KC) {
#pragma unroll
            for (int i = 0; i < PER_THR; ++i)
                st[i] = WG[(size_t)(kc + 1) * CHUNK8 + i * 256 + tid];
        }
        half8 a = A8[kc * 4];
#pragma unroll
        for (int nt = 0; nt < NT; ++nt) {
            half8 b = wbuf[cur][nt * 64 + lane];
            acc[nt] = __builtin_amdgcn_mfma_f32_16x16x32_f16(a, b, acc[nt], 0, 0, 0);
        }
        if (kc + 1 < KC) {
#pragma unroll
            for (int i = 0; i < PER_THR; ++i) wbuf[cur ^ 1][i * 256 + tid] = st[i];
        }
        __syncthreads();
    }

#pragma unroll
    for (int nt = 0; nt < NT; ++nt) {
#pragma unroll
        for (int reg = 0; reg < 4; ++reg) {
            int rr = r0 + quad * 4 + reg;
            if (rr >= M) continue;
            float v = acc[nt][reg];
            if (RELU) v = fmaxf(v + bias[nt * 16 + li], 0.f);
            outp[(size_t)rr * ldo + nt * 16 + li] = (h16)v;
        }
    }
}

template<int KC, int NT, bool RELU, bool DUAL>
__global__ __launch_bounds__(256) void gemm_lds(
        const h16* __restrict__ Xh,
        const h16* __restrict__ Wp0, const h16* __restrict__ Wp1,
        const float* __restrict__ bias,
        h16* __restrict__ out0, h16* __restrict__ out1, int M) {
    const h16* Wp = (DUAL && blockIdx.y) ? Wp1 : Wp0;
    h16* outp = (DUAL && blockIdx.y) ? out1 : out0;
    gemm_body<KC, NT, RELU>(Xh, Wp, bias, outp, M, blockIdx.x);
}

// ---- scatter_src (8 edges/thread, independent atomic chains) || h0 GEMM ---
__global__ __launch_bounds__(256) void scatter_gemm0(
        const int* __restrict__ ei, int E,
        int* __restrict__ cursor, int* __restrict__ csr_src, int GS,
        const h16* __restrict__ xh, const h16* __restrict__ Wp_in,
        const float* __restrict__ b_in, h16* __restrict__ H0h, int M) {
    if ((int)blockIdx.x < GS) {
        int base = blockIdx.x * 2048 + threadIdx.x;
        int e[8], d[8], p[8], s[8];
#pragma unroll
        for (int k = 0; k < 8; ++k) e[k] = base + k * 256;
#pragma unroll
        for (int k = 0; k < 8; ++k) d[k] = (e[k] < E) ? ei[E + e[k]] : 0;
#pragma unroll
        for (int k = 0; k < 8; ++k) p[k] = (e[k] < E) ? atomicAdd(&cursor[d[k]], 1) : 0;
#pragma unroll
        for (int k = 0; k < 8; ++k) s[k] = (e[k] < E) ? ei[e[k]] : 0;
#pragma unroll
        for (int k = 0; k < 8; ++k) if (e[k] < E) csr_src[p[k]] = s[k];
    } else {
        gemm_body<4, 4, true>(xh, Wp_in, b_in, H0h, M, blockIdx.x - GS);
    }
}

// ---- fused 4-head attention + BN + ReLU (+residual), 2 dst/wave, f16 -----
// 32 lanes per dst, 8 channels per lane (b128 gathers). Head = 8 lanes ->
// 3-stage shfl reduce. Consecutive dsts. 128-thread blocks (2 waves): finer
// retirement granularity, less per-block straggler skew. att weights are
// pre-scaled by log2e so exp uses exp2f (single v_exp_f32).
__global__ __launch_bounds__(128) void attn4_bn(
                         int N, const h16* __restrict__ XL,
                         const h16* __restrict__ XR,
                         const float* __restrict__ att,
                         const int* __restrict__ rowstart, const int* __restrict__ deg,
                         const int* __restrict__ csr_src,
                         const float* __restrict__ gamma, const float* __restrict__ beta,
                         const float* __restrict__ mean, const float* __restrict__ var,
                         const float* __restrict__ bias, const h16* __restrict__ resid,
                         h16* __restrict__ outb) {
    int wv = blockIdx.x * (blockDim.x >> 6) + (threadIdx.x >> 6);
    int d0 = wv * 2;
    if (d0 >= N) return;
    int lane = threadIdx.x & 63;
    int sl   = lane & 31;                 // lane within the 32-lane half
    int dh   = d0 + (lane >> 5);          // this half's dst
    bool dvalid = dh < N;
    int dr = dvalid ? dh : d0;

    int start = rowstart[dr];
    int dg    = deg[dr];
    int nreal = dg + 1;                   // self-loop included in CSR
    int npad  = (dg + 4) & ~3;            // row padded to multiple of 4
    int npmax = max(npad, __shfl_xor(npad, 32, 64));

    union H8 { uint4 u; half2v h[4]; };
    H8 bv, wt;
    bv.u = *(const uint4*)(XR + (size_t)dr * 256 + sl * 8);
    {
        const float LOG2E = 1.44269504088896340736f;   // folded into logits
        const float* ar = att + (sl >> 3) * 64 + (sl & 7) * 8;
        float4 wa = *(const float4*)ar;
        float4 wb = *(const float4*)(ar + 4);
        wt.h[0] = half2v{(h16)(wa.x * LOG2E), (h16)(wa.y * LOG2E)};
        wt.h[1] = half2v{(h16)(wa.z * LOG2E), (h16)(wa.w * LOG2E)};
        wt.h[2] = half2v{(h16)(wb.x * LOG2E), (h16)(wb.y * LOG2E)};
        wt.h[3] = half2v{(h16)(wb.z * LOG2E), (h16)(wb.w * LOG2E)};
    }
    const h16 k02 = (h16)0.2f;
    const uint4* XLv = (const uint4*)XL;   // 16B units; row stride = 32 units

    auto ep = [&](const H8& x) -> h16 {
        half2v q{(h16)0, (h16)0};
#pragma unroll
        for (int j = 0; j < 4; ++j) {
            half2v e  = x.h[j] + bv.h[j];
            half2v lr = __builtin_elementwise_max(e, e * k02);
            q += lr * wt.h[j];
        }
        return q.x + q.y;
    };

    float l = 0.f;
    half2v acc[4] = {half2v{(h16)0,(h16)0}, half2v{(h16)0,(h16)0},
                     half2v{(h16)0,(h16)0}, half2v{(h16)0,(h16)0}};

    int4 iv = *(const int4*)(csr_src + start);    // npad >= 4 always
    for (int i = 0; i < npmax; i += 4) {
        int4 cur = iv;
        if (i + 4 < npmax) {
            int nxt = min(i + 4, npad - 4);       // clamp: finished half re-reads
            iv = *(const int4*)(csr_src + start + nxt);
        }
        H8 x0, x1, x2, x3;
        x0.u = XLv[(size_t)(unsigned)cur.x * 32 + sl];
        x1.u = XLv[(size_t)(unsigned)cur.y * 32 + sl];
        x2.u = XLv[(size_t)(unsigned)cur.z * 32 + sl];
        x3.u = XLv[(size_t)(unsigned)cur.w * 32 + sl];
        half2v p01 = { ep(x0), ep(x1) };
        half2v p23 = { ep(x2), ep(x3) };
#pragma unroll
        for (int s = 1; s < 8; s <<= 1) {         // 8 lanes per head
            p01 += shfl_xor_h2(p01, s);
            p23 += shfl_xor_h2(p23, s);
        }
        int rem = nreal - i;
        float e0 = (rem > 0) ? exp2f((float)p01.x) : 0.f;
        float e1 = (rem > 1) ? exp2f((float)p01.y) : 0.f;
        float e2 = (rem > 2) ? exp2f((float)p23.x) : 0.f;
        float e3 = (rem > 3) ? exp2f((float)p23.y) : 0.f;
        l += (e0 + e1) + (e2 + e3);
        h16 h0 = (h16)e0, h1 = (h16)e1, h2 = (h16)e2, h3 = (h16)e3;
        half2v eb0{h0,h0}, eb1{h1,h1}, eb2{h2,h2}, eb3{h3,h3};
#pragma unroll
        for (int j = 0; j < 4; ++j) {
            acc[j] += eb0 * x0.h[j];
            acc[j] += eb1 * x1.h[j];
            acc[j] += eb2 * x2.h[j];
            acc[j] += eb3 * x3.h[j];
        }
    }

    float inv = 1.f / l;
    float oc[8];
#pragma unroll
    for (int j = 0; j < 4; ++j) { oc[2*j] = (float)acc[j].x; oc[2*j+1] = (float)acc[j].y; }
    const float4* g4  = (const float4*)gamma;
    const float4* be4 = (const float4*)beta;
    const float4* mu4 = (const float4*)mean;
    const float4* va4 = (const float4*)var;
    const float4* bi4 = (const float4*)bias;
    float o[8];
#pragma unroll
    for (int q = 0; q < 2; ++q) {
        float4 g  = g4[sl*2+q],  bb = be4[sl*2+q], mu = mu4[sl*2+q];
        float4 va = va4[sl*2+q], bi = bi4[sl*2+q];
        float s0 = g.x * rsqrtf(va.x + 1e-5f);
        float s1 = g.y * rsqrtf(va.y + 1e-5f);
        float s2 = g.z * rsqrtf(va.z + 1e-5f);
        float s3 = g.w * rsqrtf(va.w + 1e-5f);
        o[q*4+0] = fmaxf(oc[q*4+0]*inv*s0 + (bi.x-mu.x)*s0 + bb.x, 0.f);
        o[q*4+1] = fmaxf(oc[q*4+1]*inv*s1 + (bi.y-mu.y)*s1 + bb.y, 0.f);
        o[q*4+2] = fmaxf(oc[q*4+2]*inv*s2 + (bi.z-mu.z)*s2 + bb.z, 0.f);
        o[q*4+3] = fmaxf(oc[q*4+3]*inv*s3 + (bi.w-mu.w)*s3 + bb.w, 0.f);
    }
    if (resid) {
        H8 rv; rv.u = *(const uint4*)(resid + (size_t)dr * 256 + sl * 8);
#pragma unroll
        for (int j = 0; j < 4; ++j) {
            o[2*j]   += (float)rv.h[j].x;
            o[2*j+1] += (float)rv.h[j].y;
        }
    }
    if (dvalid) {
        H8 ov;
#pragma unroll
        for (int j = 0; j < 4; ++j) ov.h[j] = half2v{(h16)o[2*j], (h16)o[2*j+1]};
        *(uint4*)(outb + (size_t)dh * 256 + sl * 8) = ov.u;
    }
}

// ---- layer 2 projections from f16 input: 16 lanes/node, K=256 ----
__global__ void gemm2_wave(const h16* __restrict__ X, const float* __restrict__ Wl,
                           const float* __restrict__ Wr, float* __restrict__ xl2,
                           float* __restrict__ xr2, int N) {
    int t = blockIdx.x * blockDim.x + threadIdx.x;
    int n = t >> 4;
    int sl = t & 15;
    if (n >= N) return;
    const half4v* Xr = (const half4v*)(X + (size_t)n * 256);
    const float4* Wl4 = (const float4*)Wl;
    const float4* Wr4 = (const float4*)Wr;
    float l0 = 0.f, l1 = 0.f, r0 = 0.f, r1 = 0.f;
#pragma unroll
    for (int j = 0; j < 4; ++j) {
        int idx = sl + j * 16;
        half4v xh = Xr[idx];
        float4 xv = { (float)xh.x, (float)xh.y, (float)xh.z, (float)xh.w };
        float4 wa = Wl4[idx * 2];
        float4 wb = Wl4[idx * 2 + 1];
        l0 += xv.x * wa.x + xv.y * wa.z + xv.z * wb.x + xv.w * wb.z;
        l1 += xv.x * wa.y + xv.y * wa.w + xv.z * wb.y + xv.w * wb.w;
        wa = Wr4[idx * 2]; wb = Wr4[idx * 2 + 1];
        r0 += xv.x * wa.x + xv.y * wa.z + xv.z * wb.x + xv.w * wb.z;
        r1 += xv.x * wa.y + xv.y * wa.w + xv.z * wb.y + xv.w * wb.w;
    }
#pragma unroll
    for (int off = 1; off < 16; off <<= 1) {
        l0 += __shfl_xor(l0, off, 64);
        l1 += __shfl_xor(l1, off, 64);
        r0 += __shfl_xor(r0, off, 64);
        r1 += __shfl_xor(r1, off, 64);
    }
    if (sl == 0) {
        xl2[n * 2] = l0; xl2[n * 2 + 1] = l1;
        xr2[n * 2] = r0; xr2[n * 2 + 1] = r1;
    }
}

// ---- fused layer-2 attention (1 head, C=2) + log_softmax, 16 lanes/dst ----
__global__ void attn1_16(int N, const float* __restrict__ xl2, const float* __restrict__ xr2,
                         const float* __restrict__ att, const float* __restrict__ bias,
                         const int* __restrict__ rowstart, const int* __restrict__ deg,
                         const int* __restrict__ csr_src, float* __restrict__ out) {
    int t = blockIdx.x * blockDim.x + threadIdx.x;
    int d = t >> 4, sl = t & 15;
    if (d >= N) return;
    float a0 = att[0], a1 = att[1];
    float2 xr = ((const float2*)xr2)[d];
    float b0 = xr.x, b1 = xr.y;
    int st = rowstart[d];
    int nreal = deg[d] + 1;
    int npad  = (deg[d] + 4) & ~3;
    float l = 0.f, ac0 = 0.f, ac1 = 0.f;
    for (int i = sl; i < npad; i += 16) {
        int s = csr_src[st + i];
        float2 xv = ((const float2*)xl2)[s];
        float q = lrelu(xv.x + b0) * a0 + lrelu(xv.y + b1) * a1;
        float e = (i < nreal) ? __expf(q) : 0.f;
        l += e; ac0 += e * xv.x; ac1 += e * xv.y;
    }
#pragma unroll
    for (int off = 1; off < 16; off <<= 1) {
        l   += __shfl_xor(l, off, 64);
        ac0 += __shfl_xor(ac0, off, 64);
        ac1 += __shfl_xor(ac1, off, 64);
    }
    if (sl == 0) {
        float inv = 1.f / l;
        float v0 = ac0 * inv + bias[0];
        float v1 = ac1 * inv + bias[1];
        float mx = fmaxf(v0, v1);
        float lse = mx + logf(__expf(v0 - mx) + __expf(v1 - mx));
        out[d * 2] = v0 - lse;
        out[d * 2 + 1] = v1 - lse;
    }
}

extern "C" void kernel_launch(void* const* d_in, const int* in_sizes, int n_in,
                              void* d_out, int out_size, void* d_ws, size_t ws_size,
                              hipStream_t stream) {
    const float* x        = (const float*)d_in[0];
    const int*   ei       = (const int*)  d_in[1];
    const float* W_in     = (const float*)d_in[2];
    const float* b_in     = (const float*)d_in[3];
    const float* Wl0      = (const float*)d_in[4];
    const float* Wr0      = (const float*)d_in[5];
    const float* att0     = (const float*)d_in[6];
    const float* bias0    = (const float*)d_in[7];
    const float* Wl1      = (const float*)d_in[8];
    const float* Wr1      = (const float*)d_in[9];
    const float* att1     = (const float*)d_in[10];
    const float* bias1    = (const float*)d_in[11];
    const float* Wl2      = (const float*)d_in[12];
    const float* Wr2      = (const float*)d_in[13];
    const float* att2     = (const float*)d_in[14];
    const float* bias2    = (const float*)d_in[15];
    const float* bn_gamma = (const float*)d_in[16];
    const float* bn_beta  = (const float*)d_in[17];
    const float* bn_mean  = (const float*)d_in[18];
    const float* bn_var   = (const float*)d_in[19];

    const int N  = in_sizes[0] / 128;
    const int E  = in_sizes[1] / 2;
    const int NB = (N + 255) / 256;

    float* ws = (float*)d_ws;
    size_t off = 0;
    float* XL2  = ws + off; off += (size_t)N * 2;
    float* XR2  = ws + off; off += (size_t)N * 2;
    h16* Ah   = (h16*)(ws + off); off += (size_t)N * 128;  // f16 xl tables [N,256]
    h16* Bh   = (h16*)(ws + off); off += (size_t)N * 128;  // f16 xr tables [N,256]
    h16* Ch   = (h16*)(ws + off); off += (size_t)N * 128;  // f16 layer0 out / residual
    h16* Dh   = (h16*)(ws + off); off += (size_t)N * 128;  // f16 layer1 out
    h16* H0h  = (h16*)(ws + off); off += (size_t)N * 32;   // f16 h0 [N,64]
    h16* xh   = (h16*)(ws + off); off += (size_t)N * 64;   // f16 x  [N,128]
    h16* Wp_in = (h16*)(ws + off); off += 4096;    // 128*64
    h16* Wp_l0 = (h16*)(ws + off); off += 8192;    // 64*256
    h16* Wp_r0 = (h16*)(ws + off); off += 8192;
    h16* Wp_l1 = (h16*)(ws + off); off += 32768;   // 256*256
    h16* Wp_r1 = (h16*)(ws + off); off += 32768;
    int* ip = (int*)(ws + off);
    int* deg      = ip;              ip += N;
    int* rowstart = ip;              ip += N;
    int* cursor   = ip;              ip += N;
    int* bsum     = ip;              ip += NB;
    int* csr_src  = ip;              ip += E + 4 * N + 64;  // padded CSR

    // deg zero
    (void)hipMemsetAsync(deg, 0, (size_t)N * sizeof(int), stream);

    // ---- weight packing + x conversion + dst histogram (one launch) ----
    const int PACK_T = 172032 + N * 32 + E;
    pack_all<<<(PACK_T + 255) / 256, 256, 0, stream>>>(
        W_in, Wl0, Wr0, Wl1, Wr1, Wp_in, Wp_l0, Wp_r0, Wp_l1, Wp_r1,
        (const float4*)x, (half4v*)xh, N * 32, ei, E, deg);

    // ---- CSR build (parallel scan, padded rows incl. self-loop) ----
    scan_blk<<<NB, 256, 0, stream>>>(deg, rowstart, bsum, N);
    scan_off<<<1, 256, 0, stream>>>(bsum, NB);
    add_off<<<NB, 256, 0, stream>>>(bsum, deg, rowstart, cursor, csr_src, N);

    const int GBM = (N + 63) / 64;
    const int GS  = (E + 2047) / 2048;   // 8 edges per thread

    // scatter edges into CSR  ||  h0 = relu(x @ W_in + b_in) -> f16
    scatter_gemm0<<<GS + GBM, 256, 0, stream>>>(ei, E, cursor, csr_src, GS,
                                                xh, Wp_in, b_in, H0h, N);

    // -------- layer 0 --------
    gemm_lds<2, 16, false, true><<<dim3(GBM, 2), 256, 0, stream>>>(
        H0h, Wp_l0, Wp_r0, nullptr, Ah, Bh, N);
    attn4_bn<<<(N + 3) / 4, 128, 0, stream>>>(N, Ah, Bh, att0,
                                              rowstart, deg, csr_src,
                                              bn_gamma, bn_beta, bn_mean, bn_var,
                                              bias0, nullptr, Ch);

    // -------- layer 1 (residual) --------
    gemm_lds<8, 16, false, true><<<dim3(GBM, 2), 256, 0, stream>>>(
        Ch, Wp_l1, Wp_r1, nullptr, Ah, Bh, N);
    attn4_bn<<<(N + 3) / 4, 128, 0, stream>>>(N, Ah, Bh, att1,
                                              rowstart, deg, csr_src,
                                              bn_gamma + 256, bn_beta + 256, bn_mean + 256,
                                              bn_var + 256, bias1, Ch, Dh);

    // -------- layer 2 (1 head, C=2) + log_softmax --------
    gemm2_wave<<<(N * 16 + 255) / 256, 256, 0, stream>>>(Dh, Wl2, Wr2, XL2, XR2, N);
    attn1_16<<<(N * 16 + 255) / 256, 256, 0, stream>>>(N, XL2, XR2, att2, bias2,
                                                       rowstart, deg, csr_src, (float*)d_out);
}

// Round 15
// 383.396 us; speedup vs baseline: 1.0507x; 1.0507x over previous
//
#include <hip/hip_runtime.h>
#include <hip/hip_bf16.h>
#include <math.h>

// ---------------------------------------------------------------------------
// GATv2 3-layer GNN. CSR-by-dst padded to 4-edge batches (self-loop folded
// in); f16 MFMA GEMMs; BN/ReLU/residual fused into attention.
// R13 measured: 128-thread attn blocks REGRESSED (occ 66->60, 69.2us) ->
// revert to 256-thread blocks (397us config). Keep exp2f fold (fewer insts).
// R13 counters: attn is memory-side bound (3.54 TB/s sustained ~= duration;
// VALU time 39us < mem time). New: XL table (the gathered side, ~200MB of
// FETCH) stored fp8 e4m3 (HW cvt on read, ~8 insts/edge/lane); XR/resid/out
// stay f16. Halves gather bytes; R0 verified fp8-table precision.
// R14: unchanged resubmission — R13 bench failed with GPUAcquisitionTimeout
// (infra); predictions still open.
// ---------------------------------------------------------------------------

using h16     = _Float16;
using half2v  = __attribute__((ext_vector_type(2))) h16;
using half4v  = __attribute__((ext_vector_type(4))) h16;
using half8   = __attribute__((ext_vector_type(8))) h16;
using floatx2 = __attribute__((ext_vector_type(2))) float;
using floatx4 = __attribute__((ext_vector_type(4))) float;

__device__ __forceinline__ float lrelu(float x) { return x > 0.f ? x : 0.2f * x; }

__device__ __forceinline__ half2v shfl_xor_h2(half2v v, int mask) {
    float f = __builtin_bit_cast(float, v);
    f = __shfl_xor(f, mask, 64);
    return __builtin_bit_cast(half2v, f);
}

union H8 { uint4 u; half2v h[4]; };

// 4 fp8 (one dword) -> half4 via HW cvt
__device__ __forceinline__ half4v cvt_fp8x4(unsigned v) {
    floatx2 lo = __builtin_amdgcn_cvt_pk_f32_fp8((int)v, false);
    floatx2 hi = __builtin_amdgcn_cvt_pk_f32_fp8((int)v, true);
    half4v r = { (h16)lo.x, (h16)lo.y, (h16)hi.x, (h16)hi.y };
    return r;
}

// 8 fp8 (uint2) -> H8 (8 f16 channels)
__device__ __forceinline__ H8 cvt_fp8x8(uint2 v) {
    half4v a = cvt_fp8x4(v.x);
    half4v b = cvt_fp8x4(v.y);
    H8 r;
    r.h[0] = a.xy; r.h[1] = a.zw;
    r.h[2] = b.xy; r.h[3] = b.zw;
    return r;
}

// ---------------- CSR build ----------------
// padded row length = ceil((deg+1)/4)*4  (self-loop + pads)
__global__ __launch_bounds__(256) void scan_blk(const int* __restrict__ deg,
                                                int* __restrict__ rowstart,
                                                int* __restrict__ bsum, int N) {
    int t = blockIdx.x * 256 + threadIdx.x;
    int lane = threadIdx.x & 63, wid = threadIdx.x >> 6;
    int v = (t < N) ? ((deg[t] + 4) & ~3) : 0;
    int x = v;
#pragma unroll
    for (int off = 1; off < 64; off <<= 1) {
        int y = __shfl_up(x, off, 64);
        if (lane >= off) x += y;
    }
    __shared__ int wsum[4];
    if (lane == 63) wsum[wid] = x;
    __syncthreads();
    int add = 0;
#pragma unroll
    for (int w = 0; w < 4; ++w) if (w < wid) add += wsum[w];
    int incl = x + add;
    if (t < N) rowstart[t] = incl - v;
    if (threadIdx.x == 255) bsum[blockIdx.x] = incl;
}

__global__ __launch_bounds__(256) void scan_off(int* __restrict__ bsum, int NB) {
    int t = threadIdx.x;
    int lane = t & 63, wid = t >> 6;
    int v = (t < NB) ? bsum[t] : 0;
    int x = v;
#pragma unroll
    for (int off = 1; off < 64; off <<= 1) {
        int y = __shfl_up(x, off, 64);
        if (lane >= off) x += y;
    }
    __shared__ int wsum[4];
    if (lane == 63) wsum[wid] = x;
    __syncthreads();
    int add = 0;
#pragma unroll
    for (int w = 0; w < 4; ++w) if (w < wid) add += wsum[w];
    if (t < NB) bsum[t] = x + add - v;
}

__global__ void add_off(const int* __restrict__ bsum, const int* __restrict__ deg,
                        int* __restrict__ rowstart, int* __restrict__ cursor,
                        int* __restrict__ csr_src, int N) {
    int t = blockIdx.x * 256 + threadIdx.x;
    if (t >= N) return;
    int r = rowstart[t] + bsum[blockIdx.x];
    rowstart[t] = r;
    cursor[t] = r;
    int dg = deg[t];
    int npad = (dg + 4) & ~3;
    for (int k = dg; k < npad; ++k) csr_src[r + k] = t;
}

// ------- weight packing + x conversion + dst histogram (one launch) -------
__device__ __forceinline__ void pack_one(const float* __restrict__ W,
                                         h16* __restrict__ Wp,
                                         int t, int K, int NC) {
    int j = t & 7;
    int l = (t >> 3) & 63;
    int rest = t >> 9;
    int NT = NC >> 4;
    int nt = rest % NT;
    int kc = rest / NT;
    int row = kc * 32 + (l >> 4) * 8 + j;
    int col = nt * 16 + (l & 15);
    Wp[t] = (h16)W[(size_t)row * NC + col];
}

__global__ void pack_all(const float* __restrict__ W_in,
                         const float* __restrict__ Wl0, const float* __restrict__ Wr0,
                         const float* __restrict__ Wl1, const float* __restrict__ Wr1,
                         h16* __restrict__ P_in,
                         h16* __restrict__ P_l0, h16* __restrict__ P_r0,
                         h16* __restrict__ P_l1, h16* __restrict__ P_r1,
                         const float4* __restrict__ x, half4v* __restrict__ xh, int n4,
                         const int* __restrict__ ei, int E, int* __restrict__ deg) {
    int t = blockIdx.x * blockDim.x + threadIdx.x;
    if (t < 8192)        pack_one(W_in, P_in, t, 128, 64);
    else if (t < 24576)  pack_one(Wl0, P_l0, t - 8192, 64, 256);
    else if (t < 40960)  pack_one(Wr0, P_r0, t - 24576, 64, 256);
    else if (t < 106496) pack_one(Wl1, P_l1, t - 40960, 256, 256);
    else if (t < 172032) pack_one(Wr1, P_r1, t - 106496, 256, 256);
    else if (t < 172032 + n4) {
        int u = t - 172032;
        float4 v = x[u];
        half4v o = { (h16)v.x, (h16)v.y, (h16)v.z, (h16)v.w };
        xh[u] = o;
    } else {
        int u = t - 172032 - n4;
        if (u < E) atomicAdd(&deg[ei[E + u]], 1);   // no-return atomic: throughput-ok
    }
}

// --------- MFMA GEMM body, double-buffered LDS staging of W ----------------
// OUT8: write fp8 e4m3 instead of f16 (attention XL table).
template<int KC, int NT, bool RELU, bool OUT8>
__device__ __forceinline__ void gemm_body(const h16* __restrict__ Xh,
                                          const h16* __restrict__ Wp,
                                          const float* __restrict__ bias,
                                          void* __restrict__ outp, int M, int bx) {
    constexpr int K = KC * 32;
    constexpr int ldo = NT * 16;
    constexpr int CHUNK8 = NT * 64;
    constexpr int PER_THR = CHUNK8 / 256;
    __shared__ half8 wbuf[2][CHUNK8];

    const half8* WG = (const half8*)Wp;
    const int tid = threadIdx.x;
    const int wid = tid >> 6, lane = tid & 63;
    const int quad = lane >> 4, li = lane & 15;
    const int r0 = bx * 64 + wid * 16;
    int arow = r0 + li; if (arow >= M) arow = M - 1;
    const half8* A8 = (const half8*)Xh + (size_t)arow * (K / 8) + quad;

    floatx4 acc[NT];
#pragma unroll
    for (int t = 0; t < NT; ++t) acc[t] = (floatx4){0.f, 0.f, 0.f, 0.f};

    half8 st[PER_THR];
#pragma unroll
    for (int i = 0; i < PER_THR; ++i) st[i] = WG[i * 256 + tid];
#pragma unroll
    for (int i = 0; i < PER_THR; ++i) wbuf[0][i * 256 + tid] = st[i];
    __syncthreads();

#pragma unroll
    for (int kc = 0; kc < KC; ++kc) {
        int cur = kc & 1;
        if (kc + 1 < KC) {
#pragma unroll
            for (int i = 0; i < PER_THR; ++i)
                st[i] = WG[(size_t)(kc + 1) * CHUNK8 + i * 256 + tid];
        }
        half8 a = A8[kc * 4];
#pragma unroll
        for (int nt = 0; nt < NT; ++nt) {
            half8 b = wbuf[cur][nt * 64 + lane];
            acc[nt] = __builtin_amdgcn_mfma_f32_16x16x32_f16(a, b, acc[nt], 0, 0, 0);
        }
        if (kc + 1 < KC) {
#pragma unroll
            for (int i = 0; i < PER_THR; ++i) wbuf[cur ^ 1][i * 256 + tid] = st[i];
        }
        __syncthreads();
    }

#pragma unroll
    for (int nt = 0; nt < NT; ++nt) {
#pragma unroll
        for (int reg = 0; reg < 4; ++reg) {
            int rr = r0 + quad * 4 + reg;
            if (rr >= M) continue;
            float v = acc[nt][reg];
            if (RELU) v = fmaxf(v + bias[nt * 16 + li], 0.f);
            if (OUT8) {
                int pk = __builtin_amdgcn_cvt_pk_fp8_f32(v, v, 0, false);
                ((unsigned char*)outp)[(size_t)rr * ldo + nt * 16 + li] = (unsigned char)pk;
            } else {
                ((h16*)outp)[(size_t)rr * ldo + nt * 16 + li] = (h16)v;
            }
        }
    }
}

// DUAL grid.y: y==0 -> out0 (fp8 if OUT8L), y==1 -> out1 (f16)
template<int KC, int NT, bool RELU, bool DUAL, bool OUT8L>
__global__ __launch_bounds__(256) void gemm_lds(
        const h16* __restrict__ Xh,
        const h16* __restrict__ Wp0, const h16* __restrict__ Wp1,
        const float* __restrict__ bias,
        void* __restrict__ out0, void* __restrict__ out1, int M) {
    if (DUAL && blockIdx.y) {
        gemm_body<KC, NT, RELU, false>(Xh, Wp1, bias, out1, M, blockIdx.x);
    } else {
        gemm_body<KC, NT, RELU, OUT8L>(Xh, Wp0, bias, out0, M, blockIdx.x);
    }
}

// ---- scatter_src (8 edges/thread, independent atomic chains) || h0 GEMM ---
__global__ __launch_bounds__(256) void scatter_gemm0(
        const int* __restrict__ ei, int E,
        int* __restrict__ cursor, int* __restrict__ csr_src, int GS,
        const h16* __restrict__ xh, const h16* __restrict__ Wp_in,
        const float* __restrict__ b_in, h16* __restrict__ H0h, int M) {
    if ((int)blockIdx.x < GS) {
        int base = blockIdx.x * 2048 + threadIdx.x;
        int e[8], d[8], p[8], s[8];
#pragma unroll
        for (int k = 0; k < 8; ++k) e[k] = base + k * 256;
#pragma unroll
        for (int k = 0; k < 8; ++k) d[k] = (e[k] < E) ? ei[E + e[k]] : 0;
#pragma unroll
        for (int k = 0; k < 8; ++k) p[k] = (e[k] < E) ? atomicAdd(&cursor[d[k]], 1) : 0;
#pragma unroll
        for (int k = 0; k < 8; ++k) s[k] = (e[k] < E) ? ei[e[k]] : 0;
#pragma unroll
        for (int k = 0; k < 8; ++k) if (e[k] < E) csr_src[p[k]] = s[k];
    } else {
        gemm_body<4, 4, true, false>(xh, Wp_in, b_in, H0h, M, blockIdx.x - GS);
    }
}

// ---- fused 4-head attention + BN + ReLU (+residual), 2 dst/wave --------
// XL table fp8 (gathered side, HW cvt on read); XR/resid/out f16.
// 32 lanes per dst, 8 channels per lane. Head = 8 lanes -> 3-stage shfl.
// 256-thread blocks (measured best). att weights pre-scaled by log2e,
// exp via exp2f (single v_exp_f32).
__global__ __launch_bounds__(256) void attn4_bn(
                         int N, const unsigned char* __restrict__ XL8,
                         const h16* __restrict__ XR,
                         const float* __restrict__ att,
                         const int* __restrict__ rowstart, const int* __restrict__ deg,
                         const int* __restrict__ csr_src,
                         const float* __restrict__ gamma, const float* __restrict__ beta,
                         const float* __restrict__ mean, const float* __restrict__ var,
                         const float* __restrict__ bias, const h16* __restrict__ resid,
                         h16* __restrict__ outb) {
    int wv = blockIdx.x * (blockDim.x >> 6) + (threadIdx.x >> 6);
    int d0 = wv * 2;
    if (d0 >= N) return;
    int lane = threadIdx.x & 63;
    int sl   = lane & 31;                 // lane within the 32-lane half
    int dh   = d0 + (lane >> 5);          // this half's dst
    bool dvalid = dh < N;
    int dr = dvalid ? dh : d0;

    int start = rowstart[dr];
    int dg    = deg[dr];
    int nreal = dg + 1;                   // self-loop included in CSR
    int npad  = (dg + 4) & ~3;            // row padded to multiple of 4
    int npmax = max(npad, __shfl_xor(npad, 32, 64));

    H8 bv, wt;
    bv.u = *(const uint4*)(XR + (size_t)dr * 256 + sl * 8);
    {
        const float LOG2E = 1.44269504088896340736f;   // folded into logits
        const float* ar = att + (sl >> 3) * 64 + (sl & 7) * 8;
        float4 wa = *(const float4*)ar;
        float4 wb = *(const float4*)(ar + 4);
        wt.h[0] = half2v{(h16)(wa.x * LOG2E), (h16)(wa.y * LOG2E)};
        wt.h[1] = half2v{(h16)(wa.z * LOG2E), (h16)(wa.w * LOG2E)};
        wt.h[2] = half2v{(h16)(wb.x * LOG2E), (h16)(wb.y * LOG2E)};
        wt.h[3] = half2v{(h16)(wb.z * LOG2E), (h16)(wb.w * LOG2E)};
    }
    const h16 k02 = (h16)0.2f;
    const uint2* XLv = (const uint2*)XL8;  // 8B = 8 fp8 ch; row stride 32 units

    auto ep = [&](const H8& x) -> h16 {
        half2v q{(h16)0, (h16)0};
#pragma unroll
        for (int j = 0; j < 4; ++j) {
            half2v e  = x.h[j] + bv.h[j];
            half2v lr = __builtin_elementwise_max(e, e * k02);
            q += lr * wt.h[j];
        }
        return q.x + q.y;
    };

    float l = 0.f;
    half2v acc[4] = {half2v{(h16)0,(h16)0}, half2v{(h16)0,(h16)0},
                     half2v{(h16)0,(h16)0}, half2v{(h16)0,(h16)0}};

    int4 iv = *(const int4*)(csr_src + start);    // npad >= 4 always
    for (int i = 0; i < npmax; i += 4) {
        int4 cur = iv;
        if (i + 4 < npmax) {
            int nxt = min(i + 4, npad - 4);       // clamp: finished half re-reads
            iv = *(const int4*)(csr_src + start + nxt);
        }
        uint2 v0 = XLv[(size_t)(unsigned)cur.x * 32 + sl];
        uint2 v1 = XLv[(size_t)(unsigned)cur.y * 32 + sl];
        uint2 v2 = XLv[(size_t)(unsigned)cur.z * 32 + sl];
        uint2 v3 = XLv[(size_t)(unsigned)cur.w * 32 + sl];
        H8 x0 = cvt_fp8x8(v0);
        H8 x1 = cvt_fp8x8(v1);
        H8 x2 = cvt_fp8x8(v2);
        H8 x3 = cvt_fp8x8(v3);
        half2v p01 = { ep(x0), ep(x1) };
        half2v p23 = { ep(x2), ep(x3) };
#pragma unroll
        for (int s = 1; s < 8; s <<= 1) {         // 8 lanes per head
            p01 += shfl_xor_h2(p01, s);
            p23 += shfl_xor_h2(p23, s);
        }
        int rem = nreal - i;
        float e0 = (rem > 0) ? exp2f((float)p01.x) : 0.f;
        float e1 = (rem > 1) ? exp2f((float)p01.y) : 0.f;
        float e2 = (rem > 2) ? exp2f((float)p23.x) : 0.f;
        float e3 = (rem > 3) ? exp2f((float)p23.y) : 0.f;
        l += (e0 + e1) + (e2 + e3);
        h16 h0 = (h16)e0, h1 = (h16)e1, h2 = (h16)e2, h3 = (h16)e3;
        half2v eb0{h0,h0}, eb1{h1,h1}, eb2{h2,h2}, eb3{h3,h3};
#pragma unroll
        for (int j = 0; j < 4; ++j) {
            acc[j] += eb0 * x0.h[j];
            acc[j] += eb1 * x1.h[j];
            acc[j] += eb2 * x2.h[j];
            acc[j] += eb3 * x3.h[j];
        }
    }

    float inv = 1.f / l;
    float oc[8];
#pragma unroll
    for (int j = 0; j < 4; ++j) { oc[2*j] = (float)acc[j].x; oc[2*j+1] = (float)acc[j].y; }
    const float4* g4  = (const float4*)gamma;
    const float4* be4 = (const float4*)beta;
    const float4* mu4 = (const float4*)mean;
    const float4* va4 = (const float4*)var;
    const float4* bi4 = (const float4*)bias;
    float o[8];
#pragma unroll
    for (int q = 0; q < 2; ++q) {
        float4 g  = g4[sl*2+q],  bb = be4[sl*2+q], mu = mu4[sl*2+q];
        float4 va = va4[sl*2+q], bi = bi4[sl*2+q];
        float s0 = g.x * rsqrtf(va.x + 1e-5f);
        float s1 = g.y * rsqrtf(va.y + 1e-5f);
        float s2 = g.z * rsqrtf(va.z + 1e-5f);
        float s3 = g.w * rsqrtf(va.w + 1e-5f);
        o[q*4+0] = fmaxf(oc[q*4+0]*inv*s0 + (bi.x-mu.x)*s0 + bb.x, 0.f);
        o[q*4+1] = fmaxf(oc[q*4+1]*inv*s1 + (bi.y-mu.y)*s1 + bb.y, 0.f);
        o[q*4+2] = fmaxf(oc[q*4+2]*inv*s2 + (bi.z-mu.z)*s2 + bb.z, 0.f);
        o[q*4+3] = fmaxf(oc[q*4+3]*inv*s3 + (bi.w-mu.w)*s3 + bb.w, 0.f);
    }
    if (resid) {
        H8 rv; rv.u = *(const uint4*)(resid + (size_t)dr * 256 + sl * 8);
#pragma unroll
        for (int j = 0; j < 4; ++j) {
            o[2*j]   += (float)rv.h[j].x;
            o[2*j+1] += (float)rv.h[j].y;
        }
    }
    if (dvalid) {
        H8 ov;
#pragma unroll
        for (int j = 0; j < 4; ++j) ov.h[j] = half2v{(h16)o[2*j], (h16)o[2*j+1]};
        *(uint4*)(outb + (size_t)dh * 256 + sl * 8) = ov.u;
    }
}

// ---- layer 2 projections from f16 input: 16 lanes/node, K=256 ----
__global__ void gemm2_wave(const h16* __restrict__ X, const float* __restrict__ Wl,
                           const float* __restrict__ Wr, float* __restrict__ xl2,
                           float* __restrict__ xr2, int N) {
    int t = blockIdx.x * blockDim.x + threadIdx.x;
    int n = t >> 4;
    int sl = t & 15;
    if (n >= N) return;
    const half4v* Xr = (const half4v*)(X + (size_t)n * 256);
    const float4* Wl4 = (const float4*)Wl;
    const float4* Wr4 = (const float4*)Wr;
    float l0 = 0.f, l1 = 0.f, r0 = 0.f, r1 = 0.f;
#pragma unroll
    for (int j = 0; j < 4; ++j) {
        int idx = sl + j * 16;
        half4v xh = Xr[idx];
        float4 xv = { (float)xh.x, (float)xh.y, (float)xh.z, (float)xh.w };
        float4 wa = Wl4[idx * 2];
        float4 wb = Wl4[idx * 2 + 1];
        l0 += xv.x * wa.x + xv.y * wa.z + xv.z * wb.x + xv.w * wb.z;
        l1 += xv.x * wa.y + xv.y * wa.w + xv.z * wb.y + xv.w * wb.w;
        wa = Wr4[idx * 2]; wb = Wr4[idx * 2 + 1];
        r0 += xv.x * wa.x + xv.y * wa.z + xv.z * wb.x + xv.w * wb.z;
        r1 += xv.x * wa.y + xv.y * wa.w + xv.z * wb.y + xv.w * wb.w;
    }
#pragma unroll
    for (int off = 1; off < 16; off <<= 1) {
        l0 += __shfl_xor(l0, off, 64);
        l1 += __shfl_xor(l1, off, 64);
        r0 += __shfl_xor(r0, off, 64);
        r1 += __shfl_xor(r1, off, 64);
    }
    if (sl == 0) {
        xl2[n * 2] = l0; xl2[n * 2 + 1] = l1;
        xr2[n * 2] = r0; xr2[n * 2 + 1] = r1;
    }
}

// ---- fused layer-2 attention (1 head, C=2) + log_softmax, 16 lanes/dst ----
__global__ void attn1_16(int N, const float* __restrict__ xl2, const float* __restrict__ xr2,
                         const float* __restrict__ att, const float* __restrict__ bias,
                         const int* __restrict__ rowstart, const int* __restrict__ deg,
                         const int* __restrict__ csr_src, float* __restrict__ out) {
    int t = blockIdx.x * blockDim.x + threadIdx.x;
    int d = t >> 4, sl = t & 15;
    if (d >= N) return;
    float a0 = att[0], a1 = att[1];
    float2 xr = ((const float2*)xr2)[d];
    float b0 = xr.x, b1 = xr.y;
    int st = rowstart[d];
    int nreal = deg[d] + 1;
    int npad  = (deg[d] + 4) & ~3;
    float l = 0.f, ac0 = 0.f, ac1 = 0.f;
    for (int i = sl; i < npad; i += 16) {
        int s = csr_src[st + i];
        float2 xv = ((const float2*)xl2)[s];
        float q = lrelu(xv.x + b0) * a0 + lrelu(xv.y + b1) * a1;
        float e = (i < nreal) ? __expf(q) : 0.f;
        l += e; ac0 += e * xv.x; ac1 += e * xv.y;
    }
#pragma unroll
    for (int off = 1; off < 16; off <<= 1) {
        l   += __shfl_xor(l, off, 64);
        ac0 += __shfl_xor(ac0, off, 64);
        ac1 += __shfl_xor(ac1, off, 64);
    }
    if (sl == 0) {
        float inv = 1.f / l;
        float v0 = ac0 * inv + bias[0];
        float v1 = ac1 * inv + bias[1];
        float mx = fmaxf(v0, v1);
        float lse = mx + logf(__expf(v0 - mx) + __expf(v1 - mx));
        out[d * 2] = v0 - lse;
        out[d * 2 + 1] = v1 - lse;
    }
}

extern "C" void kernel_launch(void* const* d_in, const int* in_sizes, int n_in,
                              void* d_out, int out_size, void* d_ws, size_t ws_size,
                              hipStream_t stream) {
    const float* x        = (const float*)d_in[0];
    const int*   ei       = (const int*)  d_in[1];
    const float* W_in     = (const float*)d_in[2];
    const float* b_in     = (const float*)d_in[3];
    const float* Wl0      = (const float*)d_in[4];
    const float* Wr0      = (const float*)d_in[5];
    const float* att0     = (const float*)d_in[6];
    const float* bias0    = (const float*)d_in[7];
    const float* Wl1      = (const float*)d_in[8];
    const float* Wr1      = (const float*)d_in[9];
    const float* att1     = (const float*)d_in[10];
    const float* bias1    = (const float*)d_in[11];
    const float* Wl2      = (const float*)d_in[12];
    const float* Wr2      = (const float*)d_in[13];
    const float* att2     = (const float*)d_in[14];
    const float* bias2    = (const float*)d_in[15];
    const float* bn_gamma = (const float*)d_in[16];
    const float* bn_beta  = (const float*)d_in[17];
    const float* bn_mean  = (const float*)d_in[18];
    const float* bn_var   = (const float*)d_in[19];

    const int N  = in_sizes[0] / 128;
    const int E  = in_sizes[1] / 2;
    const int NB = (N + 255) / 256;

    float* ws = (float*)d_ws;
    size_t off = 0;
    float* XL2  = ws + off; off += (size_t)N * 2;
    float* XR2  = ws + off; off += (size_t)N * 2;
    unsigned char* A8 = (unsigned char*)(ws + off); off += (size_t)N * 64;  // fp8 xl [N,256]
    h16* Bh   = (h16*)(ws + off); off += (size_t)N * 128;  // f16 xr tables [N,256]
    h16* Ch   = (h16*)(ws + off); off += (size_t)N * 128;  // f16 layer0 out / residual
    h16* Dh   = (h16*)(ws + off); off += (size_t)N * 128;  // f16 layer1 out
    h16* H0h  = (h16*)(ws + off); off += (size_t)N * 32;   // f16 h0 [N,64]
    h16* xh   = (h16*)(ws + off); off += (size_t)N * 64;   // f16 x  [N,128]
    h16* Wp_in = (h16*)(ws + off); off += 4096;    // 128*64
    h16* Wp_l0 = (h16*)(ws + off); off += 8192;    // 64*256
    h16* Wp_r0 = (h16*)(ws + off); off += 8192;
    h16* Wp_l1 = (h16*)(ws + off); off += 32768;   // 256*256
    h16* Wp_r1 = (h16*)(ws + off); off += 32768;
    int* ip = (int*)(ws + off);
    int* deg      = ip;              ip += N;
    int* rowstart = ip;              ip += N;
    int* cursor   = ip;              ip += N;
    int* bsum     = ip;              ip += NB;
    int* csr_src  = ip;              ip += E + 4 * N + 64;  // padded CSR

    // deg zero
    (void)hipMemsetAsync(deg, 0, (size_t)N * sizeof(int), stream);

    // ---- weight packing + x conversion + dst histogram (one launch) ----
    const int PACK_T = 172032 + N * 32 + E;
    pack_all<<<(PACK_T + 255) / 256, 256, 0, stream>>>(
        W_in, Wl0, Wr0, Wl1, Wr1, Wp_in, Wp_l0, Wp_r0, Wp_l1, Wp_r1,
        (const float4*)x, (half4v*)xh, N * 32, ei, E, deg);

    // ---- CSR build (parallel scan, padded rows incl. self-loop) ----
    scan_blk<<<NB, 256, 0, stream>>>(deg, rowstart, bsum, N);
    scan_off<<<1, 256, 0, stream>>>(bsum, NB);
    add_off<<<NB, 256, 0, stream>>>(bsum, deg, rowstart, cursor, csr_src, N);

    const int GBM = (N + 63) / 64;
    const int GS  = (E + 2047) / 2048;   // 8 edges per thread

    // scatter edges into CSR  ||  h0 = relu(x @ W_in + b_in) -> f16
    scatter_gemm0<<<GS + GBM, 256, 0, stream>>>(ei, E, cursor, csr_src, GS,
                                                xh, Wp_in, b_in, H0h, N);

    // -------- layer 0 --------
    gemm_lds<2, 16, false, true, true><<<dim3(GBM, 2), 256, 0, stream>>>(
        H0h, Wp_l0, Wp_r0, nullptr, A8, Bh, N);
    attn4_bn<<<(N + 7) / 8, 256, 0, stream>>>(N, A8, Bh, att0,
                                              rowstart, deg, csr_src,
                                              bn_gamma, bn_beta, bn_mean, bn_var,
                                              bias0, nullptr, Ch);

    // -------- layer 1 (residual) --------
    gemm_lds<8, 16, false, true, true><<<dim3(GBM, 2), 256, 0, stream>>>(
        Ch, Wp_l1, Wp_r1, nullptr, A8, Bh, N);
    attn4_bn<<<(N + 7) / 8, 256, 0, stream>>>(N, A8, Bh, att1,
                                              rowstart, deg, csr_src,
                                              bn_gamma + 256, bn_beta + 256, bn_mean + 256,
                                              bn_var + 256, bias1, Ch, Dh);

    // -------- layer 2 (1 head, C=2) + log_softmax --------
    gemm2_wave<<<(N * 16 + 255) / 256, 256, 0, stream>>>(Dh, Wl2, Wr2, XL2, XR2, N);
    attn1_16<<<(N * 16 + 255) / 256, 256, 0, stream>>>(N, XL2, XR2, att2, bias2,
                                                       rowstart, deg, csr_src, (float*)d_out);
}

// Round 17
// 381.105 us; speedup vs baseline: 1.0570x; 1.0060x over previous
//
#include <hip/hip_runtime.h>
#include <hip/hip_bf16.h>
#include <math.h>

// ---------------------------------------------------------------------------
// GATv2 3-layer GNN. CSR-by-dst padded to 4-edge batches (self-loop folded
// in); f16 MFMA GEMMs; BN/ReLU/residual fused into attention.
// R15 measured: 383us best; attn at joint VALU/mem optimum (fp8 XL, FETCH
// halved). R15 design: split edge scatter across both pre-attn GEMM launches.
// R16: R15 crashed (device abort) — scatter8 used one param for BOTH the
// edge-range bound and the dst-array offset; first-half call passed E2 as
// the offset, reading src IDs as dst IDs -> cursor overrun -> OOB writes.
// Fix: separate dst-offset (always true E) from range bound (elim).
// ---------------------------------------------------------------------------

using h16     = _Float16;
using half2v  = __attribute__((ext_vector_type(2))) h16;
using half4v  = __attribute__((ext_vector_type(4))) h16;
using half8   = __attribute__((ext_vector_type(8))) h16;
using floatx2 = __attribute__((ext_vector_type(2))) float;
using floatx4 = __attribute__((ext_vector_type(4))) float;

__device__ __forceinline__ float lrelu(float x) { return x > 0.f ? x : 0.2f * x; }

__device__ __forceinline__ half2v shfl_xor_h2(half2v v, int mask) {
    float f = __builtin_bit_cast(float, v);
    f = __shfl_xor(f, mask, 64);
    return __builtin_bit_cast(half2v, f);
}

union H8 { uint4 u; half2v h[4]; };

// 4 fp8 (one dword) -> half4 via HW cvt
__device__ __forceinline__ half4v cvt_fp8x4(unsigned v) {
    floatx2 lo = __builtin_amdgcn_cvt_pk_f32_fp8((int)v, false);
    floatx2 hi = __builtin_amdgcn_cvt_pk_f32_fp8((int)v, true);
    half4v r = { (h16)lo.x, (h16)lo.y, (h16)hi.x, (h16)hi.y };
    return r;
}

// 8 fp8 (uint2) -> H8 (8 f16 channels)
__device__ __forceinline__ H8 cvt_fp8x8(uint2 v) {
    half4v a = cvt_fp8x4(v.x);
    half4v b = cvt_fp8x4(v.y);
    H8 r;
    r.h[0] = a.xy; r.h[1] = a.zw;
    r.h[2] = b.xy; r.h[3] = b.zw;
    return r;
}

// ---------------- CSR build ----------------
// padded row length = ceil((deg+1)/4)*4  (self-loop + pads)
__global__ __launch_bounds__(256) void scan_blk(const int* __restrict__ deg,
                                                int* __restrict__ rowstart,
                                                int* __restrict__ bsum, int N) {
    int t = blockIdx.x * 256 + threadIdx.x;
    int lane = threadIdx.x & 63, wid = threadIdx.x >> 6;
    int v = (t < N) ? ((deg[t] + 4) & ~3) : 0;
    int x = v;
#pragma unroll
    for (int off = 1; off < 64; off <<= 1) {
        int y = __shfl_up(x, off, 64);
        if (lane >= off) x += y;
    }
    __shared__ int wsum[4];
    if (lane == 63) wsum[wid] = x;
    __syncthreads();
    int add = 0;
#pragma unroll
    for (int w = 0; w < 4; ++w) if (w < wid) add += wsum[w];
    int incl = x + add;
    if (t < N) rowstart[t] = incl - v;
    if (threadIdx.x == 255) bsum[blockIdx.x] = incl;
}

__global__ __launch_bounds__(256) void scan_off(int* __restrict__ bsum, int NB) {
    int t = threadIdx.x;
    int lane = t & 63, wid = t >> 6;
    int v = (t < NB) ? bsum[t] : 0;
    int x = v;
#pragma unroll
    for (int off = 1; off < 64; off <<= 1) {
        int y = __shfl_up(x, off, 64);
        if (lane >= off) x += y;
    }
    __shared__ int wsum[4];
    if (lane == 63) wsum[wid] = x;
    __syncthreads();
    int add = 0;
#pragma unroll
    for (int w = 0; w < 4; ++w) if (w < wid) add += wsum[w];
    if (t < NB) bsum[t] = x + add - v;
}

__global__ void add_off(const int* __restrict__ bsum, const int* __restrict__ deg,
                        int* __restrict__ rowstart, int* __restrict__ cursor,
                        int* __restrict__ csr_src, int N) {
    int t = blockIdx.x * 256 + threadIdx.x;
    if (t >= N) return;
    int r = rowstart[t] + bsum[blockIdx.x];
    rowstart[t] = r;
    cursor[t] = r;
    int dg = deg[t];
    int npad = (dg + 4) & ~3;
    for (int k = dg; k < npad; ++k) csr_src[r + k] = t;
}

// ------- weight packing + x conversion + dst histogram (one launch) -------
__device__ __forceinline__ void pack_one(const float* __restrict__ W,
                                         h16* __restrict__ Wp,
                                         int t, int K, int NC) {
    int j = t & 7;
    int l = (t >> 3) & 63;
    int rest = t >> 9;
    int NT = NC >> 4;
    int nt = rest % NT;
    int kc = rest / NT;
    int row = kc * 32 + (l >> 4) * 8 + j;
    int col = nt * 16 + (l & 15);
    Wp[t] = (h16)W[(size_t)row * NC + col];
}

__global__ void pack_all(const float* __restrict__ W_in,
                         const float* __restrict__ Wl0, const float* __restrict__ Wr0,
                         const float* __restrict__ Wl1, const float* __restrict__ Wr1,
                         h16* __restrict__ P_in,
                         h16* __restrict__ P_l0, h16* __restrict__ P_r0,
                         h16* __restrict__ P_l1, h16* __restrict__ P_r1,
                         const float4* __restrict__ x, half4v* __restrict__ xh, int n4,
                         const int* __restrict__ ei, int E, int* __restrict__ deg) {
    int t = blockIdx.x * blockDim.x + threadIdx.x;
    if (t < 8192)        pack_one(W_in, P_in, t, 128, 64);
    else if (t < 24576)  pack_one(Wl0, P_l0, t - 8192, 64, 256);
    else if (t < 40960)  pack_one(Wr0, P_r0, t - 24576, 64, 256);
    else if (t < 106496) pack_one(Wl1, P_l1, t - 40960, 256, 256);
    else if (t < 172032) pack_one(Wr1, P_r1, t - 106496, 256, 256);
    else if (t < 172032 + n4) {
        int u = t - 172032;
        float4 v = x[u];
        half4v o = { (h16)v.x, (h16)v.y, (h16)v.z, (h16)v.w };
        xh[u] = o;
    } else {
        int u = t - 172032 - n4;
        if (u < E) atomicAdd(&deg[ei[E + u]], 1);   // no-return atomic: throughput-ok
    }
}

// --------- MFMA GEMM body, double-buffered LDS staging of W ----------------
// OUT8: write fp8 e4m3 instead of f16 (attention XL table).
template<int KC, int NT, bool RELU, bool OUT8>
__device__ __forceinline__ void gemm_body(const h16* __restrict__ Xh,
                                          const h16* __restrict__ Wp,
                                          const float* __restrict__ bias,
                                          void* __restrict__ outp, int M, int bx) {
    constexpr int K = KC * 32;
    constexpr int ldo = NT * 16;
    constexpr int CHUNK8 = NT * 64;
    constexpr int PER_THR = CHUNK8 / 256;
    __shared__ half8 wbuf[2][CHUNK8];

    const half8* WG = (const half8*)Wp;
    const int tid = threadIdx.x;
    const int wid = tid >> 6, lane = tid & 63;
    const int quad = lane >> 4, li = lane & 15;
    const int r0 = bx * 64 + wid * 16;
    int arow = r0 + li; if (arow >= M) arow = M - 1;
    const half8* A8 = (const half8*)Xh + (size_t)arow * (K / 8) + quad;

    floatx4 acc[NT];
#pragma unroll
    for (int t = 0; t < NT; ++t) acc[t] = (floatx4){0.f, 0.f, 0.f, 0.f};

    half8 st[PER_THR];
#pragma unroll
    for (int i = 0; i < PER_THR; ++i) st[i] = WG[i * 256 + tid];
#pragma unroll
    for (int i = 0; i < PER_THR; ++i) wbuf[0][i * 256 + tid] = st[i];
    __syncthreads();

#pragma unroll
    for (int kc = 0; kc < KC; ++kc) {
        int cur = kc & 1;
        if (kc + 1 < KC) {
#pragma unroll
            for (int i = 0; i < PER_THR; ++i)
                st[i] = WG[(size_t)(kc + 1) * CHUNK8 + i * 256 + tid];
        }
        half8 a = A8[kc * 4];
#pragma unroll
        for (int nt = 0; nt < NT; ++nt) {
            half8 b = wbuf[cur][nt * 64 + lane];
            acc[nt] = __builtin_amdgcn_mfma_f32_16x16x32_f16(a, b, acc[nt], 0, 0, 0);
        }
        if (kc + 1 < KC) {
#pragma unroll
            for (int i = 0; i < PER_THR; ++i) wbuf[cur ^ 1][i * 256 + tid] = st[i];
        }
        __syncthreads();
    }

#pragma unroll
    for (int nt = 0; nt < NT; ++nt) {
#pragma unroll
        for (int reg = 0; reg < 4; ++reg) {
            int rr = r0 + quad * 4 + reg;
            if (rr >= M) continue;
            float v = acc[nt][reg];
            if (RELU) v = fmaxf(v + bias[nt * 16 + li], 0.f);
            if (OUT8) {
                int pk = __builtin_amdgcn_cvt_pk_fp8_f32(v, v, 0, false);
                ((unsigned char*)outp)[(size_t)rr * ldo + nt * 16 + li] = (unsigned char)pk;
            } else {
                ((h16*)outp)[(size_t)rr * ldo + nt * 16 + li] = (h16)v;
            }
        }
    }
}

// DUAL grid.y: y==0 -> out0 (fp8 if OUT8L), y==1 -> out1 (f16)
template<int KC, int NT, bool RELU, bool DUAL, bool OUT8L>
__global__ __launch_bounds__(256) void gemm_lds(
        const h16* __restrict__ Xh,
        const h16* __restrict__ Wp0, const h16* __restrict__ Wp1,
        const float* __restrict__ bias,
        void* __restrict__ out0, void* __restrict__ out1, int M) {
    if (DUAL && blockIdx.y) {
        gemm_body<KC, NT, RELU, false>(Xh, Wp1, bias, out1, M, blockIdx.x);
    } else {
        gemm_body<KC, NT, RELU, OUT8L>(Xh, Wp0, bias, out0, M, blockIdx.x);
    }
}

// ---- edge scatter helper: 8 edges/thread, independent atomic chains ------
// E    = true edge count (dst row of ei lives at ei+E)   -- offset role
// elim = exclusive upper bound of the edge range handled -- bound role
__device__ __forceinline__ void scatter8(const int* __restrict__ ei, int E, int elim,
                                         int ebase, int* __restrict__ cursor,
                                         int* __restrict__ csr_src, int bx) {
    int base = ebase + bx * 2048 + threadIdx.x;
    int e[8], d[8], p[8], s[8];
#pragma unroll
    for (int k = 0; k < 8; ++k) e[k] = base + k * 256;
#pragma unroll
    for (int k = 0; k < 8; ++k) d[k] = (e[k] < elim) ? ei[E + e[k]] : 0;
#pragma unroll
    for (int k = 0; k < 8; ++k) p[k] = (e[k] < elim) ? atomicAdd(&cursor[d[k]], 1) : 0;
#pragma unroll
    for (int k = 0; k < 8; ++k) s[k] = (e[k] < elim) ? ei[e[k]] : 0;
#pragma unroll
    for (int k = 0; k < 8; ++k) if (e[k] < elim) csr_src[p[k]] = s[k];
}

// ---- scatter (first half of edges) || h0 GEMM ----------------------------
__global__ __launch_bounds__(256) void scatter_gemm0(
        const int* __restrict__ ei, int E2, int E,
        int* __restrict__ cursor, int* __restrict__ csr_src, int GS,
        const h16* __restrict__ xh, const h16* __restrict__ Wp_in,
        const float* __restrict__ b_in, h16* __restrict__ H0h, int M) {
    if ((int)blockIdx.x < GS) {
        scatter8(ei, E, E2 < E ? E2 : E, 0, cursor, csr_src, blockIdx.x);
    } else {
        gemm_body<4, 4, true, false>(xh, Wp_in, b_in, H0h, M, blockIdx.x - GS);
    }
}

// ---- scatter (second half of edges) || layer-0 dual GEMM -----------------
__global__ __launch_bounds__(256) void scatter_gemmL0(
        const int* __restrict__ ei, int E2, int E,
        int* __restrict__ cursor, int* __restrict__ csr_src, int GS, int GBM,
        const h16* __restrict__ H0h,
        const h16* __restrict__ Wp_l0, const h16* __restrict__ Wp_r0,
        unsigned char* __restrict__ A8, h16* __restrict__ Bh, int M) {
    if ((int)blockIdx.x < GS) {
        scatter8(ei, E, E, E2, cursor, csr_src, blockIdx.x);
    } else if ((int)blockIdx.x < GS + GBM) {
        gemm_body<2, 16, false, true>(H0h, Wp_l0, nullptr, A8, M, blockIdx.x - GS);
    } else {
        gemm_body<2, 16, false, false>(H0h, Wp_r0, nullptr, Bh, M, blockIdx.x - GS - GBM);
    }
}

// ---- fused 4-head attention + BN + ReLU (+residual), 2 dst/wave --------
// XL table fp8 (gathered side, HW cvt on read); XR/resid/out f16.
// 32 lanes per dst, 8 channels per lane. Head = 8 lanes -> 3-stage shfl.
// 256-thread blocks (measured best). att weights pre-scaled by log2e,
// exp via exp2f (single v_exp_f32).
__global__ __launch_bounds__(256) void attn4_bn(
                         int N, const unsigned char* __restrict__ XL8,
                         const h16* __restrict__ XR,
                         const float* __restrict__ att,
                         const int* __restrict__ rowstart, const int* __restrict__ deg,
                         const int* __restrict__ csr_src,
                         const float* __restrict__ gamma, const float* __restrict__ beta,
                         const float* __restrict__ mean, const float* __restrict__ var,
                         const float* __restrict__ bias, const h16* __restrict__ resid,
                         h16* __restrict__ outb) {
    int wv = blockIdx.x * (blockDim.x >> 6) + (threadIdx.x >> 6);
    int d0 = wv * 2;
    if (d0 >= N) return;
    int lane = threadIdx.x & 63;
    int sl   = lane & 31;                 // lane within the 32-lane half
    int dh   = d0 + (lane >> 5);          // this half's dst
    bool dvalid = dh < N;
    int dr = dvalid ? dh : d0;

    int start = rowstart[dr];
    int dg    = deg[dr];
    int nreal = dg + 1;                   // self-loop included in CSR
    int npad  = (dg + 4) & ~3;            // row padded to multiple of 4
    int npmax = max(npad, __shfl_xor(npad, 32, 64));

    H8 bv, wt;
    bv.u = *(const uint4*)(XR + (size_t)dr * 256 + sl * 8);
    {
        const float LOG2E = 1.44269504088896340736f;   // folded into logits
        const float* ar = att + (sl >> 3) * 64 + (sl & 7) * 8;
        float4 wa = *(const float4*)ar;
        float4 wb = *(const float4*)(ar + 4);
        wt.h[0] = half2v{(h16)(wa.x * LOG2E), (h16)(wa.y * LOG2E)};
        wt.h[1] = half2v{(h16)(wa.z * LOG2E), (h16)(wa.w * LOG2E)};
        wt.h[2] = half2v{(h16)(wb.x * LOG2E), (h16)(wb.y * LOG2E)};
        wt.h[3] = half2v{(h16)(wb.z * LOG2E), (h16)(wb.w * LOG2E)};
    }
    const h16 k02 = (h16)0.2f;
    const uint2* XLv = (const uint2*)XL8;  // 8B = 8 fp8 ch; row stride 32 units

    auto ep = [&](const H8& x) -> h16 {
        half2v q{(h16)0, (h16)0};
#pragma unroll
        for (int j = 0; j < 4; ++j) {
            half2v e  = x.h[j] + bv.h[j];
            half2v lr = __builtin_elementwise_max(e, e * k02);
            q += lr * wt.h[j];
        }
        return q.x + q.y;
    };

    float l = 0.f;
    half2v acc[4] = {half2v{(h16)0,(h16)0}, half2v{(h16)0,(h16)0},
                     half2v{(h16)0,(h16)0}, half2v{(h16)0,(h16)0}};

    int4 iv = *(const int4*)(csr_src + start);    // npad >= 4 always
    for (int i = 0; i < npmax; i += 4) {
        int4 cur = iv;
        if (i + 4 < npmax) {
            int nxt = min(i + 4, npad - 4);       // clamp: finished half re-reads
            iv = *(const int4*)(csr_src + start + nxt);
        }
        uint2 v0 = XLv[(size_t)(unsigned)cur.x * 32 + sl];
        uint2 v1 = XLv[(size_t)(unsigned)cur.y * 32 + sl];
        uint2 v2 = XLv[(size_t)(unsigned)cur.z * 32 + sl];
        uint2 v3 = XLv[(size_t)(unsigned)cur.w * 32 + sl];
        H8 x0 = cvt_fp8x8(v0);
        H8 x1 = cvt_fp8x8(v1);
        H8 x2 = cvt_fp8x8(v2);
        H8 x3 = cvt_fp8x8(v3);
        half2v p01 = { ep(x0), ep(x1) };
        half2v p23 = { ep(x2), ep(x3) };
#pragma unroll
        for (int s = 1; s < 8; s <<= 1) {         // 8 lanes per head
            p01 += shfl_xor_h2(p01, s);
            p23 += shfl_xor_h2(p23, s);
        }
        int rem = nreal - i;
        float e0 = (rem > 0) ? exp2f((float)p01.x) : 0.f;
        float e1 = (rem > 1) ? exp2f((float)p01.y) : 0.f;
        float e2 = (rem > 2) ? exp2f((float)p23.x) : 0.f;
        float e3 = (rem > 3) ? exp2f((float)p23.y) : 0.f;
        l += (e0 + e1) + (e2 + e3);
        h16 h0 = (h16)e0, h1 = (h16)e1, h2 = (h16)e2, h3 = (h16)e3;
        half2v eb0{h0,h0}, eb1{h1,h1}, eb2{h2,h2}, eb3{h3,h3};
#pragma unroll
        for (int j = 0; j < 4; ++j) {
            acc[j] += eb0 * x0.h[j];
            acc[j] += eb1 * x1.h[j];
            acc[j] += eb2 * x2.h[j];
            acc[j] += eb3 * x3.h[j];
        }
    }

    float inv = 1.f / l;
    float oc[8];
#pragma unroll
    for (int j = 0; j < 4; ++j) { oc[2*j] = (float)acc[j].x; oc[2*j+1] = (float)acc[j].y; }
    const float4* g4  = (const float4*)gamma;
    const float4* be4 = (const float4*)beta;
    const float4* mu4 = (const float4*)mean;
    const float4* va4 = (const float4*)var;
    const float4* bi4 = (const float4*)bias;
    float o[8];
#pragma unroll
    for (int q = 0; q < 2; ++q) {
        float4 g  = g4[sl*2+q],  bb = be4[sl*2+q], mu = mu4[sl*2+q];
        float4 va = va4[sl*2+q], bi = bi4[sl*2+q];
        float s0 = g.x * rsqrtf(va.x + 1e-5f);
        float s1 = g.y * rsqrtf(va.y + 1e-5f);
        float s2 = g.z * rsqrtf(va.z + 1e-5f);
        float s3 = g.w * rsqrtf(va.w + 1e-5f);
        o[q*4+0] = fmaxf(oc[q*4+0]*inv*s0 + (bi.x-mu.x)*s0 + bb.x, 0.f);
        o[q*4+1] = fmaxf(oc[q*4+1]*inv*s1 + (bi.y-mu.y)*s1 + bb.y, 0.f);
        o[q*4+2] = fmaxf(oc[q*4+2]*inv*s2 + (bi.z-mu.z)*s2 + bb.z, 0.f);
        o[q*4+3] = fmaxf(oc[q*4+3]*inv*s3 + (bi.w-mu.w)*s3 + bb.w, 0.f);
    }
    if (resid) {
        H8 rv; rv.u = *(const uint4*)(resid + (size_t)dr * 256 + sl * 8);
#pragma unroll
        for (int j = 0; j < 4; ++j) {
            o[2*j]   += (float)rv.h[j].x;
            o[2*j+1] += (float)rv.h[j].y;
        }
    }
    if (dvalid) {
        H8 ov;
#pragma unroll
        for (int j = 0; j < 4; ++j) ov.h[j] = half2v{(h16)o[2*j], (h16)o[2*j+1]};
        *(uint4*)(outb + (size_t)dh * 256 + sl * 8) = ov.u;
    }
}

// ---- layer 2 projections from f16 input: 16 lanes/node, K=256 ----
__global__ void gemm2_wave(const h16* __restrict__ X, const float* __restrict__ Wl,
                           const float* __restrict__ Wr, float* __restrict__ xl2,
                           float* __restrict__ xr2, int N) {
    int t = blockIdx.x * blockDim.x + threadIdx.x;
    int n = t >> 4;
    int sl = t & 15;
    if (n >= N) return;
    const half4v* Xr = (const half4v*)(X + (size_t)n * 256);
    const float4* Wl4 = (const float4*)Wl;
    const float4* Wr4 = (const float4*)Wr;
    float l0 = 0.f, l1 = 0.f, r0 = 0.f, r1 = 0.f;
#pragma unroll
    for (int j = 0; j < 4; ++j) {
        int idx = sl + j * 16;
        half4v xh = Xr[idx];
        float4 xv = { (float)xh.x, (float)xh.y, (float)xh.z, (float)xh.w };
        float4 wa = Wl4[idx * 2];
        float4 wb = Wl4[idx * 2 + 1];
        l0 += xv.x * wa.x + xv.y * wa.z + xv.z * wb.x + xv.w * wb.z;
        l1 += xv.x * wa.y + xv.y * wa.w + xv.z * wb.y + xv.w * wb.w;
        wa = Wr4[idx * 2]; wb = Wr4[idx * 2 + 1];
        r0 += xv.x * wa.x + xv.y * wa.z + xv.z * wb.x + xv.w * wb.z;
        r1 += xv.x * wa.y + xv.y * wa.w + xv.z * wb.y + xv.w * wb.w;
    }
#pragma unroll
    for (int off = 1; off < 16; off <<= 1) {
        l0 += __shfl_xor(l0, off, 64);
        l1 += __shfl_xor(l1, off, 64);
        r0 += __shfl_xor(r0, off, 64);
        r1 += __shfl_xor(r1, off, 64);
    }
    if (sl == 0) {
        xl2[n * 2] = l0; xl2[n * 2 + 1] = l1;
        xr2[n * 2] = r0; xr2[n * 2 + 1] = r1;
    }
}

// ---- fused layer-2 attention (1 head, C=2) + log_softmax, 16 lanes/dst ----
__global__ void attn1_16(int N, const float* __restrict__ xl2, const float* __restrict__ xr2,
                         const float* __restrict__ att, const float* __restrict__ bias,
                         const int* __restrict__ rowstart, const int* __restrict__ deg,
                         const int* __restrict__ csr_src, float* __restrict__ out) {
    int t = blockIdx.x * blockDim.x + threadIdx.x;
    int d = t >> 4, sl = t & 15;
    if (d >= N) return;
    float a0 = att[0], a1 = att[1];
    float2 xr = ((const float2*)xr2)[d];
    float b0 = xr.x, b1 = xr.y;
    int st = rowstart[d];
    int nreal = deg[d] + 1;
    int npad  = (deg[d] + 4) & ~3;
    float l = 0.f, ac0 = 0.f, ac1 = 0.f;
    for (int i = sl; i < npad; i += 16) {
        int s = csr_src[st + i];
        float2 xv = ((const float2*)xl2)[s];
        float q = lrelu(xv.x + b0) * a0 + lrelu(xv.y + b1) * a1;
        float e = (i < nreal) ? __expf(q) : 0.f;
        l += e; ac0 += e * xv.x; ac1 += e * xv.y;
    }
#pragma unroll
    for (int off = 1; off < 16; off <<= 1) {
        l   += __shfl_xor(l, off, 64);
        ac0 += __shfl_xor(ac0, off, 64);
        ac1 += __shfl_xor(ac1, off, 64);
    }
    if (sl == 0) {
        float inv = 1.f / l;
        float v0 = ac0 * inv + bias[0];
        float v1 = ac1 * inv + bias[1];
        float mx = fmaxf(v0, v1);
        float lse = mx + logf(__expf(v0 - mx) + __expf(v1 - mx));
        out[d * 2] = v0 - lse;
        out[d * 2 + 1] = v1 - lse;
    }
}

extern "C" void kernel_launch(void* const* d_in, const int* in_sizes, int n_in,
                              void* d_out, int out_size, void* d_ws, size_t ws_size,
                              hipStream_t stream) {
    const float* x        = (const float*)d_in[0];
    const int*   ei       = (const int*)  d_in[1];
    const float* W_in     = (const float*)d_in[2];
    const float* b_in     = (const float*)d_in[3];
    const float* Wl0      = (const float*)d_in[4];
    const float* Wr0      = (const float*)d_in[5];
    const float* att0     = (const float*)d_in[6];
    const float* bias0    = (const float*)d_in[7];
    const float* Wl1      = (const float*)d_in[8];
    const float* Wr1      = (const float*)d_in[9];
    const float* att1     = (const float*)d_in[10];
    const float* bias1    = (const float*)d_in[11];
    const float* Wl2      = (const float*)d_in[12];
    const float* Wr2      = (const float*)d_in[13];
    const float* att2     = (const float*)d_in[14];
    const float* bias2    = (const float*)d_in[15];
    const float* bn_gamma = (const float*)d_in[16];
    const float* bn_beta  = (const float*)d_in[17];
    const float* bn_mean  = (const float*)d_in[18];
    const float* bn_var   = (const float*)d_in[19];

    const int N  = in_sizes[0] / 128;
    const int E  = in_sizes[1] / 2;
    const int NB = (N + 255) / 256;

    float* ws = (float*)d_ws;
    size_t off = 0;
    float* XL2  = ws + off; off += (size_t)N * 2;
    float* XR2  = ws + off; off += (size_t)N * 2;
    unsigned char* A8 = (unsigned char*)(ws + off); off += (size_t)N * 64;  // fp8 xl [N,256]
    h16* Bh   = (h16*)(ws + off); off += (size_t)N * 128;  // f16 xr tables [N,256]
    h16* Ch   = (h16*)(ws + off); off += (size_t)N * 128;  // f16 layer0 out / residual
    h16* Dh   = (h16*)(ws + off); off += (size_t)N * 128;  // f16 layer1 out
    h16* H0h  = (h16*)(ws + off); off += (size_t)N * 32;   // f16 h0 [N,64]
    h16* xh   = (h16*)(ws + off); off += (size_t)N * 64;   // f16 x  [N,128]
    h16* Wp_in = (h16*)(ws + off); off += 4096;    // 128*64
    h16* Wp_l0 = (h16*)(ws + off); off += 8192;    // 64*256
    h16* Wp_r0 = (h16*)(ws + off); off += 8192;
    h16* Wp_l1 = (h16*)(ws + off); off += 32768;   // 256*256
    h16* Wp_r1 = (h16*)(ws + off); off += 32768;
    int* ip = (int*)(ws + off);
    int* deg      = ip;              ip += N;
    int* rowstart = ip;              ip += N;
    int* cursor   = ip;              ip += N;
    int* bsum     = ip;              ip += NB;
    int* csr_src  = ip;              ip += E + 4 * N + 64;  // padded CSR

    // deg zero
    (void)hipMemsetAsync(deg, 0, (size_t)N * sizeof(int), stream);

    // ---- weight packing + x conversion + dst histogram (one launch) ----
    const int PACK_T = 172032 + N * 32 + E;
    pack_all<<<(PACK_T + 255) / 256, 256, 0, stream>>>(
        W_in, Wl0, Wr0, Wl1, Wr1, Wp_in, Wp_l0, Wp_r0, Wp_l1, Wp_r1,
        (const float4*)x, (half4v*)xh, N * 32, ei, E, deg);

    // ---- CSR build (parallel scan, padded rows incl. self-loop) ----
    scan_blk<<<NB, 256, 0, stream>>>(deg, rowstart, bsum, N);
    scan_off<<<1, 256, 0, stream>>>(bsum, NB);
    add_off<<<NB, 256, 0, stream>>>(bsum, deg, rowstart, cursor, csr_src, N);

    const int GBM = (N + 63) / 64;
    const int E2  = ((E / 2) + 2047) & ~2047;          // first-half edge count
    const int GS0 = E2 / 2048;                          // blocks for half 1
    const int GS1 = (E - E2 + 2047) / 2048;             // blocks for half 2

    // scatter half-1  ||  h0 = relu(x @ W_in + b_in) -> f16
    scatter_gemm0<<<GS0 + GBM, 256, 0, stream>>>(ei, E2, E, cursor, csr_src, GS0,
                                                 xh, Wp_in, b_in, H0h, N);

    // scatter half-2  ||  layer-0 dual GEMM (xl->fp8 A8, xr->f16 Bh)
    scatter_gemmL0<<<GS1 + 2 * GBM, 256, 0, stream>>>(ei, E2, E, cursor, csr_src,
                                                      GS1, GBM, H0h, Wp_l0, Wp_r0,
                                                      A8, Bh, N);

    // -------- layer 0 attention --------
    attn4_bn<<<(N + 7) / 8, 256, 0, stream>>>(N, A8, Bh, att0,
                                              rowstart, deg, csr_src,
                                              bn_gamma, bn_beta, bn_mean, bn_var,
                                              bias0, nullptr, Ch);

    // -------- layer 1 (residual) --------
    gemm_lds<8, 16, false, true, true><<<dim3(GBM, 2), 256, 0, stream>>>(
        Ch, Wp_l1, Wp_r1, nullptr, A8, Bh, N);
    attn4_bn<<<(N + 7) / 8, 256, 0, stream>>>(N, A8, Bh, att1,
                                              rowstart, deg, csr_src,
                                              bn_gamma + 256, bn_beta + 256, bn_mean + 256,
                                              bn_var + 256, bias1, Ch, Dh);

    // -------- layer 2 (1 head, C=2) + log_softmax --------
    gemm2_wave<<<(N * 16 + 255) / 256, 256, 0, stream>>>(Dh, Wl2, Wr2, XL2, XR2, N);
    attn1_16<<<(N * 16 + 255) / 256, 256, 0, stream>>>(N, XL2, XR2, att2, bias2,
                                                       rowstart, deg, csr_src, (float*)d_out);
}

// Round 18
// 373.555 us; speedup vs baseline: 1.0784x; 1.0202x over previous
//
#include <hip/hip_runtime.h>
#include <hip/hip_bf16.h>
#include <math.h>

// ---------------------------------------------------------------------------
// GATv2 3-layer GNN. CSR-by-dst padded to 4-edge batches (self-loop folded
// in); f16 MFMA GEMMs; BN/ReLU/residual fused into attention.
// R17 measured: 381us best. Scatter-split gain was marginal (-2.3us) ->
// scatter already cheap after 8-chain ILP. attn at joint VALU/mem optimum.
// R17 change: fuse layer-2 projection (h @ Wl2/Wr2, 256->2 x2) into the
// layer-1 attention epilogue: each lane holds 8 ch of the final row; 32 FMA
// + 5-stage shfl reduce per lane. Deletes gemm2_wave launch, the 25MB Dh
// write and 25MB re-read; Dh buffer removed.
// ---------------------------------------------------------------------------

using h16     = _Float16;
using half2v  = __attribute__((ext_vector_type(2))) h16;
using half4v  = __attribute__((ext_vector_type(4))) h16;
using half8   = __attribute__((ext_vector_type(8))) h16;
using floatx2 = __attribute__((ext_vector_type(2))) float;
using floatx4 = __attribute__((ext_vector_type(4))) float;

__device__ __forceinline__ float lrelu(float x) { return x > 0.f ? x : 0.2f * x; }

__device__ __forceinline__ half2v shfl_xor_h2(half2v v, int mask) {
    float f = __builtin_bit_cast(float, v);
    f = __shfl_xor(f, mask, 64);
    return __builtin_bit_cast(half2v, f);
}

union H8 { uint4 u; half2v h[4]; };

// 4 fp8 (one dword) -> half4 via HW cvt
__device__ __forceinline__ half4v cvt_fp8x4(unsigned v) {
    floatx2 lo = __builtin_amdgcn_cvt_pk_f32_fp8((int)v, false);
    floatx2 hi = __builtin_amdgcn_cvt_pk_f32_fp8((int)v, true);
    half4v r = { (h16)lo.x, (h16)lo.y, (h16)hi.x, (h16)hi.y };
    return r;
}

// 8 fp8 (uint2) -> H8 (8 f16 channels)
__device__ __forceinline__ H8 cvt_fp8x8(uint2 v) {
    half4v a = cvt_fp8x4(v.x);
    half4v b = cvt_fp8x4(v.y);
    H8 r;
    r.h[0] = a.xy; r.h[1] = a.zw;
    r.h[2] = b.xy; r.h[3] = b.zw;
    return r;
}

// ---------------- CSR build ----------------
// padded row length = ceil((deg+1)/4)*4  (self-loop + pads)
__global__ __launch_bounds__(256) void scan_blk(const int* __restrict__ deg,
                                                int* __restrict__ rowstart,
                                                int* __restrict__ bsum, int N) {
    int t = blockIdx.x * 256 + threadIdx.x;
    int lane = threadIdx.x & 63, wid = threadIdx.x >> 6;
    int v = (t < N) ? ((deg[t] + 4) & ~3) : 0;
    int x = v;
#pragma unroll
    for (int off = 1; off < 64; off <<= 1) {
        int y = __shfl_up(x, off, 64);
        if (lane >= off) x += y;
    }
    __shared__ int wsum[4];
    if (lane == 63) wsum[wid] = x;
    __syncthreads();
    int add = 0;
#pragma unroll
    for (int w = 0; w < 4; ++w) if (w < wid) add += wsum[w];
    int incl = x + add;
    if (t < N) rowstart[t] = incl - v;
    if (threadIdx.x == 255) bsum[blockIdx.x] = incl;
}

__global__ __launch_bounds__(256) void scan_off(int* __restrict__ bsum, int NB) {
    int t = threadIdx.x;
    int lane = t & 63, wid = t >> 6;
    int v = (t < NB) ? bsum[t] : 0;
    int x = v;
#pragma unroll
    for (int off = 1; off < 64; off <<= 1) {
        int y = __shfl_up(x, off, 64);
        if (lane >= off) x += y;
    }
    __shared__ int wsum[4];
    if (lane == 63) wsum[wid] = x;
    __syncthreads();
    int add = 0;
#pragma unroll
    for (int w = 0; w < 4; ++w) if (w < wid) add += wsum[w];
    if (t < NB) bsum[t] = x + add - v;
}

__global__ void add_off(const int* __restrict__ bsum, const int* __restrict__ deg,
                        int* __restrict__ rowstart, int* __restrict__ cursor,
                        int* __restrict__ csr_src, int N) {
    int t = blockIdx.x * 256 + threadIdx.x;
    if (t >= N) return;
    int r = rowstart[t] + bsum[blockIdx.x];
    rowstart[t] = r;
    cursor[t] = r;
    int dg = deg[t];
    int npad = (dg + 4) & ~3;
    for (int k = dg; k < npad; ++k) csr_src[r + k] = t;
}

// ------- weight packing + x conversion + dst histogram (one launch) -------
__device__ __forceinline__ void pack_one(const float* __restrict__ W,
                                         h16* __restrict__ Wp,
                                         int t, int K, int NC) {
    int j = t & 7;
    int l = (t >> 3) & 63;
    int rest = t >> 9;
    int NT = NC >> 4;
    int nt = rest % NT;
    int kc = rest / NT;
    int row = kc * 32 + (l >> 4) * 8 + j;
    int col = nt * 16 + (l & 15);
    Wp[t] = (h16)W[(size_t)row * NC + col];
}

__global__ void pack_all(const float* __restrict__ W_in,
                         const float* __restrict__ Wl0, const float* __restrict__ Wr0,
                         const float* __restrict__ Wl1, const float* __restrict__ Wr1,
                         h16* __restrict__ P_in,
                         h16* __restrict__ P_l0, h16* __restrict__ P_r0,
                         h16* __restrict__ P_l1, h16* __restrict__ P_r1,
                         const float4* __restrict__ x, half4v* __restrict__ xh, int n4,
                         const int* __restrict__ ei, int E, int* __restrict__ deg) {
    int t = blockIdx.x * blockDim.x + threadIdx.x;
    if (t < 8192)        pack_one(W_in, P_in, t, 128, 64);
    else if (t < 24576)  pack_one(Wl0, P_l0, t - 8192, 64, 256);
    else if (t < 40960)  pack_one(Wr0, P_r0, t - 24576, 64, 256);
    else if (t < 106496) pack_one(Wl1, P_l1, t - 40960, 256, 256);
    else if (t < 172032) pack_one(Wr1, P_r1, t - 106496, 256, 256);
    else if (t < 172032 + n4) {
        int u = t - 172032;
        float4 v = x[u];
        half4v o = { (h16)v.x, (h16)v.y, (h16)v.z, (h16)v.w };
        xh[u] = o;
    } else {
        int u = t - 172032 - n4;
        if (u < E) atomicAdd(&deg[ei[E + u]], 1);   // no-return atomic: throughput-ok
    }
}

// --------- MFMA GEMM body, double-buffered LDS staging of W ----------------
// OUT8: write fp8 e4m3 instead of f16 (attention XL table).
template<int KC, int NT, bool RELU, bool OUT8>
__device__ __forceinline__ void gemm_body(const h16* __restrict__ Xh,
                                          const h16* __restrict__ Wp,
                                          const float* __restrict__ bias,
                                          void* __restrict__ outp, int M, int bx) {
    constexpr int K = KC * 32;
    constexpr int ldo = NT * 16;
    constexpr int CHUNK8 = NT * 64;
    constexpr int PER_THR = CHUNK8 / 256;
    __shared__ half8 wbuf[2][CHUNK8];

    const half8* WG = (const half8*)Wp;
    const int tid = threadIdx.x;
    const int wid = tid >> 6, lane = tid & 63;
    const int quad = lane >> 4, li = lane & 15;
    const int r0 = bx * 64 + wid * 16;
    int arow = r0 + li; if (arow >= M) arow = M - 1;
    const half8* A8 = (const half8*)Xh + (size_t)arow * (K / 8) + quad;

    floatx4 acc[NT];
#pragma unroll
    for (int t = 0; t < NT; ++t) acc[t] = (floatx4){0.f, 0.f, 0.f, 0.f};

    half8 st[PER_THR];
#pragma unroll
    for (int i = 0; i < PER_THR; ++i) st[i] = WG[i * 256 + tid];
#pragma unroll
    for (int i = 0; i < PER_THR; ++i) wbuf[0][i * 256 + tid] = st[i];
    __syncthreads();

#pragma unroll
    for (int kc = 0; kc < KC; ++kc) {
        int cur = kc & 1;
        if (kc + 1 < KC) {
#pragma unroll
            for (int i = 0; i < PER_THR; ++i)
                st[i] = WG[(size_t)(kc + 1) * CHUNK8 + i * 256 + tid];
        }
        half8 a = A8[kc * 4];
#pragma unroll
        for (int nt = 0; nt < NT; ++nt) {
            half8 b = wbuf[cur][nt * 64 + lane];
            acc[nt] = __builtin_amdgcn_mfma_f32_16x16x32_f16(a, b, acc[nt], 0, 0, 0);
        }
        if (kc + 1 < KC) {
#pragma unroll
            for (int i = 0; i < PER_THR; ++i) wbuf[cur ^ 1][i * 256 + tid] = st[i];
        }
        __syncthreads();
    }

#pragma unroll
    for (int nt = 0; nt < NT; ++nt) {
#pragma unroll
        for (int reg = 0; reg < 4; ++reg) {
            int rr = r0 + quad * 4 + reg;
            if (rr >= M) continue;
            float v = acc[nt][reg];
            if (RELU) v = fmaxf(v + bias[nt * 16 + li], 0.f);
            if (OUT8) {
                int pk = __builtin_amdgcn_cvt_pk_fp8_f32(v, v, 0, false);
                ((unsigned char*)outp)[(size_t)rr * ldo + nt * 16 + li] = (unsigned char)pk;
            } else {
                ((h16*)outp)[(size_t)rr * ldo + nt * 16 + li] = (h16)v;
            }
        }
    }
}

// DUAL grid.y: y==0 -> out0 (fp8 if OUT8L), y==1 -> out1 (f16)
template<int KC, int NT, bool RELU, bool DUAL, bool OUT8L>
__global__ __launch_bounds__(256) void gemm_lds(
        const h16* __restrict__ Xh,
        const h16* __restrict__ Wp0, const h16* __restrict__ Wp1,
        const float* __restrict__ bias,
        void* __restrict__ out0, void* __restrict__ out1, int M) {
    if (DUAL && blockIdx.y) {
        gemm_body<KC, NT, RELU, false>(Xh, Wp1, bias, out1, M, blockIdx.x);
    } else {
        gemm_body<KC, NT, RELU, OUT8L>(Xh, Wp0, bias, out0, M, blockIdx.x);
    }
}

// ---- edge scatter helper: 8 edges/thread, independent atomic chains ------
// E    = true edge count (dst row of ei lives at ei+E)   -- offset role
// elim = exclusive upper bound of the edge range handled -- bound role
__device__ __forceinline__ void scatter8(const int* __restrict__ ei, int E, int elim,
                                         int ebase, int* __restrict__ cursor,
                                         int* __restrict__ csr_src, int bx) {
    int base = ebase + bx * 2048 + threadIdx.x;
    int e[8], d[8], p[8], s[8];
#pragma unroll
    for (int k = 0; k < 8; ++k) e[k] = base + k * 256;
#pragma unroll
    for (int k = 0; k < 8; ++k) d[k] = (e[k] < elim) ? ei[E + e[k]] : 0;
#pragma unroll
    for (int k = 0; k < 8; ++k) p[k] = (e[k] < elim) ? atomicAdd(&cursor[d[k]], 1) : 0;
#pragma unroll
    for (int k = 0; k < 8; ++k) s[k] = (e[k] < elim) ? ei[e[k]] : 0;
#pragma unroll
    for (int k = 0; k < 8; ++k) if (e[k] < elim) csr_src[p[k]] = s[k];
}

// ---- scatter (first half of edges) || h0 GEMM ----------------------------
__global__ __launch_bounds__(256) void scatter_gemm0(
        const int* __restrict__ ei, int E2, int E,
        int* __restrict__ cursor, int* __restrict__ csr_src, int GS,
        const h16* __restrict__ xh, const h16* __restrict__ Wp_in,
        const float* __restrict__ b_in, h16* __restrict__ H0h, int M) {
    if ((int)blockIdx.x < GS) {
        scatter8(ei, E, E2 < E ? E2 : E, 0, cursor, csr_src, blockIdx.x);
    } else {
        gemm_body<4, 4, true, false>(xh, Wp_in, b_in, H0h, M, blockIdx.x - GS);
    }
}

// ---- scatter (second half of edges) || layer-0 dual GEMM -----------------
__global__ __launch_bounds__(256) void scatter_gemmL0(
        const int* __restrict__ ei, int E2, int E,
        int* __restrict__ cursor, int* __restrict__ csr_src, int GS, int GBM,
        const h16* __restrict__ H0h,
        const h16* __restrict__ Wp_l0, const h16* __restrict__ Wp_r0,
        unsigned char* __restrict__ A8, h16* __restrict__ Bh, int M) {
    if ((int)blockIdx.x < GS) {
        scatter8(ei, E, E, E2, cursor, csr_src, blockIdx.x);
    } else if ((int)blockIdx.x < GS + GBM) {
        gemm_body<2, 16, false, true>(H0h, Wp_l0, nullptr, A8, M, blockIdx.x - GS);
    } else {
        gemm_body<2, 16, false, false>(H0h, Wp_r0, nullptr, Bh, M, blockIdx.x - GS - GBM);
    }
}

// ---- fused 4-head attention + BN + ReLU (+residual) (+proj), 2 dst/wave --
// XL table fp8 (gathered side, HW cvt on read); XR/resid/out f16.
// 32 lanes per dst, 8 channels per lane. Head = 8 lanes -> 3-stage shfl.
// If xl2 != nullptr (layer 1): instead of writing the 25MB f16 row, project
// h @ Wl2 / Wr2 (256->2 each) in-register (32 FMA + 5-stage shfl per lane)
// and write only xl2/xr2 (f32 [N][2]) -- gemm2_wave fused away.
__global__ __launch_bounds__(256) void attn4_bn(
                         int N, const unsigned char* __restrict__ XL8,
                         const h16* __restrict__ XR,
                         const float* __restrict__ att,
                         const int* __restrict__ rowstart, const int* __restrict__ deg,
                         const int* __restrict__ csr_src,
                         const float* __restrict__ gamma, const float* __restrict__ beta,
                         const float* __restrict__ mean, const float* __restrict__ var,
                         const float* __restrict__ bias, const h16* __restrict__ resid,
                         h16* __restrict__ outb,
                         const float* __restrict__ Wl2, const float* __restrict__ Wr2,
                         float* __restrict__ xl2, float* __restrict__ xr2) {
    int wv = blockIdx.x * (blockDim.x >> 6) + (threadIdx.x >> 6);
    int d0 = wv * 2;
    if (d0 >= N) return;
    int lane = threadIdx.x & 63;
    int sl   = lane & 31;                 // lane within the 32-lane half
    int dh   = d0 + (lane >> 5);          // this half's dst
    bool dvalid = dh < N;
    int dr = dvalid ? dh : d0;

    int start = rowstart[dr];
    int dg    = deg[dr];
    int nreal = dg + 1;                   // self-loop included in CSR
    int npad  = (dg + 4) & ~3;            // row padded to multiple of 4
    int npmax = max(npad, __shfl_xor(npad, 32, 64));

    H8 bv, wt;
    bv.u = *(const uint4*)(XR + (size_t)dr * 256 + sl * 8);
    {
        const float LOG2E = 1.44269504088896340736f;   // folded into logits
        const float* ar = att + (sl >> 3) * 64 + (sl & 7) * 8;
        float4 wa = *(const float4*)ar;
        float4 wb = *(const float4*)(ar + 4);
        wt.h[0] = half2v{(h16)(wa.x * LOG2E), (h16)(wa.y * LOG2E)};
        wt.h[1] = half2v{(h16)(wa.z * LOG2E), (h16)(wa.w * LOG2E)};
        wt.h[2] = half2v{(h16)(wb.x * LOG2E), (h16)(wb.y * LOG2E)};
        wt.h[3] = half2v{(h16)(wb.z * LOG2E), (h16)(wb.w * LOG2E)};
    }
    const h16 k02 = (h16)0.2f;
    const uint2* XLv = (const uint2*)XL8;  // 8B = 8 fp8 ch; row stride 32 units

    auto ep = [&](const H8& x) -> h16 {
        half2v q{(h16)0, (h16)0};
#pragma unroll
        for (int j = 0; j < 4; ++j) {
            half2v e  = x.h[j] + bv.h[j];
            half2v lr = __builtin_elementwise_max(e, e * k02);
            q += lr * wt.h[j];
        }
        return q.x + q.y;
    };

    float l = 0.f;
    half2v acc[4] = {half2v{(h16)0,(h16)0}, half2v{(h16)0,(h16)0},
                     half2v{(h16)0,(h16)0}, half2v{(h16)0,(h16)0}};

    int4 iv = *(const int4*)(csr_src + start);    // npad >= 4 always
    for (int i = 0; i < npmax; i += 4) {
        int4 cur = iv;
        if (i + 4 < npmax) {
            int nxt = min(i + 4, npad - 4);       // clamp: finished half re-reads
            iv = *(const int4*)(csr_src + start + nxt);
        }
        uint2 v0 = XLv[(size_t)(unsigned)cur.x * 32 + sl];
        uint2 v1 = XLv[(size_t)(unsigned)cur.y * 32 + sl];
        uint2 v2 = XLv[(size_t)(unsigned)cur.z * 32 + sl];
        uint2 v3 = XLv[(size_t)(unsigned)cur.w * 32 + sl];
        H8 x0 = cvt_fp8x8(v0);
        H8 x1 = cvt_fp8x8(v1);
        H8 x2 = cvt_fp8x8(v2);
        H8 x3 = cvt_fp8x8(v3);
        half2v p01 = { ep(x0), ep(x1) };
        half2v p23 = { ep(x2), ep(x3) };
#pragma unroll
        for (int s = 1; s < 8; s <<= 1) {         // 8 lanes per head
            p01 += shfl_xor_h2(p01, s);
            p23 += shfl_xor_h2(p23, s);
        }
        int rem = nreal - i;
        float e0 = (rem > 0) ? exp2f((float)p01.x) : 0.f;
        float e1 = (rem > 1) ? exp2f((float)p01.y) : 0.f;
        float e2 = (rem > 2) ? exp2f((float)p23.x) : 0.f;
        float e3 = (rem > 3) ? exp2f((float)p23.y) : 0.f;
        l += (e0 + e1) + (e2 + e3);
        h16 h0 = (h16)e0, h1 = (h16)e1, h2 = (h16)e2, h3 = (h16)e3;
        half2v eb0{h0,h0}, eb1{h1,h1}, eb2{h2,h2}, eb3{h3,h3};
#pragma unroll
        for (int j = 0; j < 4; ++j) {
            acc[j] += eb0 * x0.h[j];
            acc[j] += eb1 * x1.h[j];
            acc[j] += eb2 * x2.h[j];
            acc[j] += eb3 * x3.h[j];
        }
    }

    float inv = 1.f / l;
    float oc[8];
#pragma unroll
    for (int j = 0; j < 4; ++j) { oc[2*j] = (float)acc[j].x; oc[2*j+1] = (float)acc[j].y; }
    const float4* g4  = (const float4*)gamma;
    const float4* be4 = (const float4*)beta;
    const float4* mu4 = (const float4*)mean;
    const float4* va4 = (const float4*)var;
    const float4* bi4 = (const float4*)bias;
    float o[8];
#pragma unroll
    for (int q = 0; q < 2; ++q) {
        float4 g  = g4[sl*2+q],  bb = be4[sl*2+q], mu = mu4[sl*2+q];
        float4 va = va4[sl*2+q], bi = bi4[sl*2+q];
        float s0 = g.x * rsqrtf(va.x + 1e-5f);
        float s1 = g.y * rsqrtf(va.y + 1e-5f);
        float s2 = g.z * rsqrtf(va.z + 1e-5f);
        float s3 = g.w * rsqrtf(va.w + 1e-5f);
        o[q*4+0] = fmaxf(oc[q*4+0]*inv*s0 + (bi.x-mu.x)*s0 + bb.x, 0.f);
        o[q*4+1] = fmaxf(oc[q*4+1]*inv*s1 + (bi.y-mu.y)*s1 + bb.y, 0.f);
        o[q*4+2] = fmaxf(oc[q*4+2]*inv*s2 + (bi.z-mu.z)*s2 + bb.z, 0.f);
        o[q*4+3] = fmaxf(oc[q*4+3]*inv*s3 + (bi.w-mu.w)*s3 + bb.w, 0.f);
    }
    if (resid) {
        H8 rv; rv.u = *(const uint4*)(resid + (size_t)dr * 256 + sl * 8);
#pragma unroll
        for (int j = 0; j < 4; ++j) {
            o[2*j]   += (float)rv.h[j].x;
            o[2*j+1] += (float)rv.h[j].y;
        }
    }
    if (xl2) {
        // fused layer-2 projection: o[k] = channel sl*8+k of h[dh]
        // Wl2/Wr2 are [256][2] row-major; lane covers 16 consecutive floats.
        const float4* wl4 = (const float4*)(Wl2 + sl * 16);
        const float4* wr4 = (const float4*)(Wr2 + sl * 16);
        float l0 = 0.f, l1 = 0.f, r0 = 0.f, r1 = 0.f;
#pragma unroll
        for (int q = 0; q < 4; ++q) {     // float4 q covers channels 2q, 2q+1
            float4 wl = wl4[q];
            float4 wr = wr4[q];
            float oa = o[2*q], ob = o[2*q+1];
            l0 += oa * wl.x + ob * wl.z;
            l1 += oa * wl.y + ob * wl.w;
            r0 += oa * wr.x + ob * wr.z;
            r1 += oa * wr.y + ob * wr.w;
        }
#pragma unroll
        for (int s2 = 1; s2 < 32; s2 <<= 1) {   // reduce within the 32-lane half
            l0 += __shfl_xor(l0, s2, 64);
            l1 += __shfl_xor(l1, s2, 64);
            r0 += __shfl_xor(r0, s2, 64);
            r1 += __shfl_xor(r1, s2, 64);
        }
        if (dvalid && sl == 0) {
            xl2[dh * 2]     = l0;
            xl2[dh * 2 + 1] = l1;
            xr2[dh * 2]     = r0;
            xr2[dh * 2 + 1] = r1;
        }
    } else if (dvalid) {
        H8 ov;
#pragma unroll
        for (int j = 0; j < 4; ++j) ov.h[j] = half2v{(h16)o[2*j], (h16)o[2*j+1]};
        *(uint4*)(outb + (size_t)dh * 256 + sl * 8) = ov.u;
    }
}

// ---- fused layer-2 attention (1 head, C=2) + log_softmax, 16 lanes/dst ----
__global__ void attn1_16(int N, const float* __restrict__ xl2, const float* __restrict__ xr2,
                         const float* __restrict__ att, const float* __restrict__ bias,
                         const int* __restrict__ rowstart, const int* __restrict__ deg,
                         const int* __restrict__ csr_src, float* __restrict__ out) {
    int t = blockIdx.x * blockDim.x + threadIdx.x;
    int d = t >> 4, sl = t & 15;
    if (d >= N) return;
    float a0 = att[0], a1 = att[1];
    float2 xr = ((const float2*)xr2)[d];
    float b0 = xr.x, b1 = xr.y;
    int st = rowstart[d];
    int nreal = deg[d] + 1;
    int npad  = (deg[d] + 4) & ~3;
    float l = 0.f, ac0 = 0.f, ac1 = 0.f;
    for (int i = sl; i < npad; i += 16) {
        int s = csr_src[st + i];
        float2 xv = ((const float2*)xl2)[s];
        float q = lrelu(xv.x + b0) * a0 + lrelu(xv.y + b1) * a1;
        float e = (i < nreal) ? __expf(q) : 0.f;
        l += e; ac0 += e * xv.x; ac1 += e * xv.y;
    }
#pragma unroll
    for (int off = 1; off < 16; off <<= 1) {
        l   += __shfl_xor(l, off, 64);
        ac0 += __shfl_xor(ac0, off, 64);
        ac1 += __shfl_xor(ac1, off, 64);
    }
    if (sl == 0) {
        float inv = 1.f / l;
        float v0 = ac0 * inv + bias[0];
        float v1 = ac1 * inv + bias[1];
        float mx = fmaxf(v0, v1);
        float lse = mx + logf(__expf(v0 - mx) + __expf(v1 - mx));
        out[d * 2] = v0 - lse;
        out[d * 2 + 1] = v1 - lse;
    }
}

extern "C" void kernel_launch(void* const* d_in, const int* in_sizes, int n_in,
                              void* d_out, int out_size, void* d_ws, size_t ws_size,
                              hipStream_t stream) {
    const float* x        = (const float*)d_in[0];
    const int*   ei       = (const int*)  d_in[1];
    const float* W_in     = (const float*)d_in[2];
    const float* b_in     = (const float*)d_in[3];
    const float* Wl0      = (const float*)d_in[4];
    const float* Wr0      = (const float*)d_in[5];
    const float* att0     = (const float*)d_in[6];
    const float* bias0    = (const float*)d_in[7];
    const float* Wl1      = (const float*)d_in[8];
    const float* Wr1      = (const float*)d_in[9];
    const float* att1     = (const float*)d_in[10];
    const float* bias1    = (const float*)d_in[11];
    const float* Wl2      = (const float*)d_in[12];
    const float* Wr2      = (const float*)d_in[13];
    const float* att2     = (const float*)d_in[14];
    const float* bias2    = (const float*)d_in[15];
    const float* bn_gamma = (const float*)d_in[16];
    const float* bn_beta  = (const float*)d_in[17];
    const float* bn_mean  = (const float*)d_in[18];
    const float* bn_var   = (const float*)d_in[19];

    const int N  = in_sizes[0] / 128;
    const int E  = in_sizes[1] / 2;
    const int NB = (N + 255) / 256;

    float* ws = (float*)d_ws;
    size_t off = 0;
    float* XL2  = ws + off; off += (size_t)N * 2;
    float* XR2  = ws + off; off += (size_t)N * 2;
    unsigned char* A8 = (unsigned char*)(ws + off); off += (size_t)N * 64;  // fp8 xl [N,256]
    h16* Bh   = (h16*)(ws + off); off += (size_t)N * 128;  // f16 xr tables [N,256]
    h16* Ch   = (h16*)(ws + off); off += (size_t)N * 128;  // f16 layer0 out / residual
    h16* H0h  = (h16*)(ws + off); off += (size_t)N * 32;   // f16 h0 [N,64]
    h16* xh   = (h16*)(ws + off); off += (size_t)N * 64;   // f16 x  [N,128]
    h16* Wp_in = (h16*)(ws + off); off += 4096;    // 128*64
    h16* Wp_l0 = (h16*)(ws + off); off += 8192;    // 64*256
    h16* Wp_r0 = (h16*)(ws + off); off += 8192;
    h16* Wp_l1 = (h16*)(ws + off); off += 32768;   // 256*256
    h16* Wp_r1 = (h16*)(ws + off); off += 32768;
    int* ip = (int*)(ws + off);
    int* deg      = ip;              ip += N;
    int* rowstart = ip;              ip += N;
    int* cursor   = ip;              ip += N;
    int* bsum     = ip;              ip += NB;
    int* csr_src  = ip;              ip += E + 4 * N + 64;  // padded CSR

    // deg zero
    (void)hipMemsetAsync(deg, 0, (size_t)N * sizeof(int), stream);

    // ---- weight packing + x conversion + dst histogram (one launch) ----
    const int PACK_T = 172032 + N * 32 + E;
    pack_all<<<(PACK_T + 255) / 256, 256, 0, stream>>>(
        W_in, Wl0, Wr0, Wl1, Wr1, Wp_in, Wp_l0, Wp_r0, Wp_l1, Wp_r1,
        (const float4*)x, (half4v*)xh, N * 32, ei, E, deg);

    // ---- CSR build (parallel scan, padded rows incl. self-loop) ----
    scan_blk<<<NB, 256, 0, stream>>>(deg, rowstart, bsum, N);
    scan_off<<<1, 256, 0, stream>>>(bsum, NB);
    add_off<<<NB, 256, 0, stream>>>(bsum, deg, rowstart, cursor, csr_src, N);

    const int GBM = (N + 63) / 64;
    const int E2  = ((E / 2) + 2047) & ~2047;          // first-half edge count
    const int GS0 = E2 / 2048;                          // blocks for half 1
    const int GS1 = (E - E2 + 2047) / 2048;             // blocks for half 2

    // scatter half-1  ||  h0 = relu(x @ W_in + b_in) -> f16
    scatter_gemm0<<<GS0 + GBM, 256, 0, stream>>>(ei, E2, E, cursor, csr_src, GS0,
                                                 xh, Wp_in, b_in, H0h, N);

    // scatter half-2  ||  layer-0 dual GEMM (xl->fp8 A8, xr->f16 Bh)
    scatter_gemmL0<<<GS1 + 2 * GBM, 256, 0, stream>>>(ei, E2, E, cursor, csr_src,
                                                      GS1, GBM, H0h, Wp_l0, Wp_r0,
                                                      A8, Bh, N);

    // -------- layer 0 attention --------
    attn4_bn<<<(N + 7) / 8, 256, 0, stream>>>(N, A8, Bh, att0,
                                              rowstart, deg, csr_src,
                                              bn_gamma, bn_beta, bn_mean, bn_var,
                                              bias0, nullptr, Ch,
                                              nullptr, nullptr, nullptr, nullptr);

    // -------- layer 1 (residual) + fused layer-2 projection --------
    gemm_lds<8, 16, false, true, true><<<dim3(GBM, 2), 256, 0, stream>>>(
        Ch, Wp_l1, Wp_r1, nullptr, A8, Bh, N);
    attn4_bn<<<(N + 7) / 8, 256, 0, stream>>>(N, A8, Bh, att1,
                                              rowstart, deg, csr_src,
                                              bn_gamma + 256, bn_beta + 256, bn_mean + 256,
                                              bn_var + 256, bias1, Ch, nullptr,
                                              Wl2, Wr2, XL2, XR2);

    // -------- layer 2 (1 head, C=2) + log_softmax --------
    attn1_16<<<(N * 16 + 255) / 256, 256, 0, stream>>>(N, XL2, XR2, att2, bias2,
                                                       rowstart, deg, csr_src, (float*)d_out);
}

// Round 19
// 369.882 us; speedup vs baseline: 1.0891x; 1.0099x over previous
//
#include <hip/hip_runtime.h>
#include <hip/hip_bf16.h>
#include <math.h>

// ---------------------------------------------------------------------------
// GATv2 3-layer GNN. CSR-by-dst padded to 4-edge batches (self-loop folded
// in); f16 MFMA GEMMs; BN/ReLU/residual fused into attention; layer-2
// projection fused into layer-1 attention epilogue (R17, -7.5us).
// R18: scatter halves are the largest unverified cost (~50us each?, VALU 1%
// = return-atomic latency). Deepen the validated ILP mechanism: 16 edges
// per thread (16 independent load->atomic->store chains).
// ---------------------------------------------------------------------------

using h16     = _Float16;
using half2v  = __attribute__((ext_vector_type(2))) h16;
using half4v  = __attribute__((ext_vector_type(4))) h16;
using half8   = __attribute__((ext_vector_type(8))) h16;
using floatx2 = __attribute__((ext_vector_type(2))) float;
using floatx4 = __attribute__((ext_vector_type(4))) float;

__device__ __forceinline__ float lrelu(float x) { return x > 0.f ? x : 0.2f * x; }

__device__ __forceinline__ half2v shfl_xor_h2(half2v v, int mask) {
    float f = __builtin_bit_cast(float, v);
    f = __shfl_xor(f, mask, 64);
    return __builtin_bit_cast(half2v, f);
}

union H8 { uint4 u; half2v h[4]; };

// 4 fp8 (one dword) -> half4 via HW cvt
__device__ __forceinline__ half4v cvt_fp8x4(unsigned v) {
    floatx2 lo = __builtin_amdgcn_cvt_pk_f32_fp8((int)v, false);
    floatx2 hi = __builtin_amdgcn_cvt_pk_f32_fp8((int)v, true);
    half4v r = { (h16)lo.x, (h16)lo.y, (h16)hi.x, (h16)hi.y };
    return r;
}

// 8 fp8 (uint2) -> H8 (8 f16 channels)
__device__ __forceinline__ H8 cvt_fp8x8(uint2 v) {
    half4v a = cvt_fp8x4(v.x);
    half4v b = cvt_fp8x4(v.y);
    H8 r;
    r.h[0] = a.xy; r.h[1] = a.zw;
    r.h[2] = b.xy; r.h[3] = b.zw;
    return r;
}

// ---------------- CSR build ----------------
// padded row length = ceil((deg+1)/4)*4  (self-loop + pads)
__global__ __launch_bounds__(256) void scan_blk(const int* __restrict__ deg,
                                                int* __restrict__ rowstart,
                                                int* __restrict__ bsum, int N) {
    int t = blockIdx.x * 256 + threadIdx.x;
    int lane = threadIdx.x & 63, wid = threadIdx.x >> 6;
    int v = (t < N) ? ((deg[t] + 4) & ~3) : 0;
    int x = v;
#pragma unroll
    for (int off = 1; off < 64; off <<= 1) {
        int y = __shfl_up(x, off, 64);
        if (lane >= off) x += y;
    }
    __shared__ int wsum[4];
    if (lane == 63) wsum[wid] = x;
    __syncthreads();
    int add = 0;
#pragma unroll
    for (int w = 0; w < 4; ++w) if (w < wid) add += wsum[w];
    int incl = x + add;
    if (t < N) rowstart[t] = incl - v;
    if (threadIdx.x == 255) bsum[blockIdx.x] = incl;
}

__global__ __launch_bounds__(256) void scan_off(int* __restrict__ bsum, int NB) {
    int t = threadIdx.x;
    int lane = t & 63, wid = t >> 6;
    int v = (t < NB) ? bsum[t] : 0;
    int x = v;
#pragma unroll
    for (int off = 1; off < 64; off <<= 1) {
        int y = __shfl_up(x, off, 64);
        if (lane >= off) x += y;
    }
    __shared__ int wsum[4];
    if (lane == 63) wsum[wid] = x;
    __syncthreads();
    int add = 0;
#pragma unroll
    for (int w = 0; w < 4; ++w) if (w < wid) add += wsum[w];
    if (t < NB) bsum[t] = x + add - v;
}

__global__ void add_off(const int* __restrict__ bsum, const int* __restrict__ deg,
                        int* __restrict__ rowstart, int* __restrict__ cursor,
                        int* __restrict__ csr_src, int N) {
    int t = blockIdx.x * 256 + threadIdx.x;
    if (t >= N) return;
    int r = rowstart[t] + bsum[blockIdx.x];
    rowstart[t] = r;
    cursor[t] = r;
    int dg = deg[t];
    int npad = (dg + 4) & ~3;
    for (int k = dg; k < npad; ++k) csr_src[r + k] = t;
}

// ------- weight packing + x conversion + dst histogram (one launch) -------
__device__ __forceinline__ void pack_one(const float* __restrict__ W,
                                         h16* __restrict__ Wp,
                                         int t, int K, int NC) {
    int j = t & 7;
    int l = (t >> 3) & 63;
    int rest = t >> 9;
    int NT = NC >> 4;
    int nt = rest % NT;
    int kc = rest / NT;
    int row = kc * 32 + (l >> 4) * 8 + j;
    int col = nt * 16 + (l & 15);
    Wp[t] = (h16)W[(size_t)row * NC + col];
}

__global__ void pack_all(const float* __restrict__ W_in,
                         const float* __restrict__ Wl0, const float* __restrict__ Wr0,
                         const float* __restrict__ Wl1, const float* __restrict__ Wr1,
                         h16* __restrict__ P_in,
                         h16* __restrict__ P_l0, h16* __restrict__ P_r0,
                         h16* __restrict__ P_l1, h16* __restrict__ P_r1,
                         const float4* __restrict__ x, half4v* __restrict__ xh, int n4,
                         const int* __restrict__ ei, int E, int* __restrict__ deg) {
    int t = blockIdx.x * blockDim.x + threadIdx.x;
    if (t < 8192)        pack_one(W_in, P_in, t, 128, 64);
    else if (t < 24576)  pack_one(Wl0, P_l0, t - 8192, 64, 256);
    else if (t < 40960)  pack_one(Wr0, P_r0, t - 24576, 64, 256);
    else if (t < 106496) pack_one(Wl1, P_l1, t - 40960, 256, 256);
    else if (t < 172032) pack_one(Wr1, P_r1, t - 106496, 256, 256);
    else if (t < 172032 + n4) {
        int u = t - 172032;
        float4 v = x[u];
        half4v o = { (h16)v.x, (h16)v.y, (h16)v.z, (h16)v.w };
        xh[u] = o;
    } else {
        int u = t - 172032 - n4;
        if (u < E) atomicAdd(&deg[ei[E + u]], 1);   // no-return atomic: throughput-ok
    }
}

// --------- MFMA GEMM body, double-buffered LDS staging of W ----------------
// OUT8: write fp8 e4m3 instead of f16 (attention XL table).
template<int KC, int NT, bool RELU, bool OUT8>
__device__ __forceinline__ void gemm_body(const h16* __restrict__ Xh,
                                          const h16* __restrict__ Wp,
                                          const float* __restrict__ bias,
                                          void* __restrict__ outp, int M, int bx) {
    constexpr int K = KC * 32;
    constexpr int ldo = NT * 16;
    constexpr int CHUNK8 = NT * 64;
    constexpr int PER_THR = CHUNK8 / 256;
    __shared__ half8 wbuf[2][CHUNK8];

    const half8* WG = (const half8*)Wp;
    const int tid = threadIdx.x;
    const int wid = tid >> 6, lane = tid & 63;
    const int quad = lane >> 4, li = lane & 15;
    const int r0 = bx * 64 + wid * 16;
    int arow = r0 + li; if (arow >= M) arow = M - 1;
    const half8* A8 = (const half8*)Xh + (size_t)arow * (K / 8) + quad;

    floatx4 acc[NT];
#pragma unroll
    for (int t = 0; t < NT; ++t) acc[t] = (floatx4){0.f, 0.f, 0.f, 0.f};

    half8 st[PER_THR];
#pragma unroll
    for (int i = 0; i < PER_THR; ++i) st[i] = WG[i * 256 + tid];
#pragma unroll
    for (int i = 0; i < PER_THR; ++i) wbuf[0][i * 256 + tid] = st[i];
    __syncthreads();

#pragma unroll
    for (int kc = 0; kc < KC; ++kc) {
        int cur = kc & 1;
        if (kc + 1 < KC) {
#pragma unroll
            for (int i = 0; i < PER_THR; ++i)
                st[i] = WG[(size_t)(kc + 1) * CHUNK8 + i * 256 + tid];
        }
        half8 a = A8[kc * 4];
#pragma unroll
        for (int nt = 0; nt < NT; ++nt) {
            half8 b = wbuf[cur][nt * 64 + lane];
            acc[nt] = __builtin_amdgcn_mfma_f32_16x16x32_f16(a, b, acc[nt], 0, 0, 0);
        }
        if (kc + 1 < KC) {
#pragma unroll
            for (int i = 0; i < PER_THR; ++i) wbuf[cur ^ 1][i * 256 + tid] = st[i];
        }
        __syncthreads();
    }

#pragma unroll
    for (int nt = 0; nt < NT; ++nt) {
#pragma unroll
        for (int reg = 0; reg < 4; ++reg) {
            int rr = r0 + quad * 4 + reg;
            if (rr >= M) continue;
            float v = acc[nt][reg];
            if (RELU) v = fmaxf(v + bias[nt * 16 + li], 0.f);
            if (OUT8) {
                int pk = __builtin_amdgcn_cvt_pk_fp8_f32(v, v, 0, false);
                ((unsigned char*)outp)[(size_t)rr * ldo + nt * 16 + li] = (unsigned char)pk;
            } else {
                ((h16*)outp)[(size_t)rr * ldo + nt * 16 + li] = (h16)v;
            }
        }
    }
}

// DUAL grid.y: y==0 -> out0 (fp8 if OUT8L), y==1 -> out1 (f16)
template<int KC, int NT, bool RELU, bool DUAL, bool OUT8L>
__global__ __launch_bounds__(256) void gemm_lds(
        const h16* __restrict__ Xh,
        const h16* __restrict__ Wp0, const h16* __restrict__ Wp1,
        const float* __restrict__ bias,
        void* __restrict__ out0, void* __restrict__ out1, int M) {
    if (DUAL && blockIdx.y) {
        gemm_body<KC, NT, RELU, false>(Xh, Wp1, bias, out1, M, blockIdx.x);
    } else {
        gemm_body<KC, NT, RELU, OUT8L>(Xh, Wp0, bias, out0, M, blockIdx.x);
    }
}

// ---- edge scatter helper: 16 edges/thread, independent atomic chains -----
// E    = true edge count (dst row of ei lives at ei+E)   -- offset role
// elim = exclusive upper bound of the edge range handled -- bound role
__device__ __forceinline__ void scatter16(const int* __restrict__ ei, int E, int elim,
                                          int ebase, int* __restrict__ cursor,
                                          int* __restrict__ csr_src, int bx) {
    int base = ebase + bx * 4096 + threadIdx.x;
    int e[16], d[16], p[16], s[16];
#pragma unroll
    for (int k = 0; k < 16; ++k) e[k] = base + k * 256;
#pragma unroll
    for (int k = 0; k < 16; ++k) d[k] = (e[k] < elim) ? ei[E + e[k]] : 0;
#pragma unroll
    for (int k = 0; k < 16; ++k) p[k] = (e[k] < elim) ? atomicAdd(&cursor[d[k]], 1) : 0;
#pragma unroll
    for (int k = 0; k < 16; ++k) s[k] = (e[k] < elim) ? ei[e[k]] : 0;
#pragma unroll
    for (int k = 0; k < 16; ++k) if (e[k] < elim) csr_src[p[k]] = s[k];
}

// ---- scatter (first half of edges) || h0 GEMM ----------------------------
__global__ __launch_bounds__(256) void scatter_gemm0(
        const int* __restrict__ ei, int E2, int E,
        int* __restrict__ cursor, int* __restrict__ csr_src, int GS,
        const h16* __restrict__ xh, const h16* __restrict__ Wp_in,
        const float* __restrict__ b_in, h16* __restrict__ H0h, int M) {
    if ((int)blockIdx.x < GS) {
        scatter16(ei, E, E2 < E ? E2 : E, 0, cursor, csr_src, blockIdx.x);
    } else {
        gemm_body<4, 4, true, false>(xh, Wp_in, b_in, H0h, M, blockIdx.x - GS);
    }
}

// ---- scatter (second half of edges) || layer-0 dual GEMM -----------------
__global__ __launch_bounds__(256) void scatter_gemmL0(
        const int* __restrict__ ei, int E2, int E,
        int* __restrict__ cursor, int* __restrict__ csr_src, int GS, int GBM,
        const h16* __restrict__ H0h,
        const h16* __restrict__ Wp_l0, const h16* __restrict__ Wp_r0,
        unsigned char* __restrict__ A8, h16* __restrict__ Bh, int M) {
    if ((int)blockIdx.x < GS) {
        scatter16(ei, E, E, E2, cursor, csr_src, blockIdx.x);
    } else if ((int)blockIdx.x < GS + GBM) {
        gemm_body<2, 16, false, true>(H0h, Wp_l0, nullptr, A8, M, blockIdx.x - GS);
    } else {
        gemm_body<2, 16, false, false>(H0h, Wp_r0, nullptr, Bh, M, blockIdx.x - GS - GBM);
    }
}

// ---- fused 4-head attention + BN + ReLU (+residual) (+proj), 2 dst/wave --
// XL table fp8 (gathered side, HW cvt on read); XR/resid/out f16.
// 32 lanes per dst, 8 channels per lane. Head = 8 lanes -> 3-stage shfl.
// If xl2 != nullptr (layer 1): project h @ Wl2 / Wr2 (256->2 each)
// in-register and write only xl2/xr2 (f32 [N][2]) -- gemm2_wave fused away.
__global__ __launch_bounds__(256) void attn4_bn(
                         int N, const unsigned char* __restrict__ XL8,
                         const h16* __restrict__ XR,
                         const float* __restrict__ att,
                         const int* __restrict__ rowstart, const int* __restrict__ deg,
                         const int* __restrict__ csr_src,
                         const float* __restrict__ gamma, const float* __restrict__ beta,
                         const float* __restrict__ mean, const float* __restrict__ var,
                         const float* __restrict__ bias, const h16* __restrict__ resid,
                         h16* __restrict__ outb,
                         const float* __restrict__ Wl2, const float* __restrict__ Wr2,
                         float* __restrict__ xl2, float* __restrict__ xr2) {
    int wv = blockIdx.x * (blockDim.x >> 6) + (threadIdx.x >> 6);
    int d0 = wv * 2;
    if (d0 >= N) return;
    int lane = threadIdx.x & 63;
    int sl   = lane & 31;                 // lane within the 32-lane half
    int dh   = d0 + (lane >> 5);          // this half's dst
    bool dvalid = dh < N;
    int dr = dvalid ? dh : d0;

    int start = rowstart[dr];
    int dg    = deg[dr];
    int nreal = dg + 1;                   // self-loop included in CSR
    int npad  = (dg + 4) & ~3;            // row padded to multiple of 4
    int npmax = max(npad, __shfl_xor(npad, 32, 64));

    H8 bv, wt;
    bv.u = *(const uint4*)(XR + (size_t)dr * 256 + sl * 8);
    {
        const float LOG2E = 1.44269504088896340736f;   // folded into logits
        const float* ar = att + (sl >> 3) * 64 + (sl & 7) * 8;
        float4 wa = *(const float4*)ar;
        float4 wb = *(const float4*)(ar + 4);
        wt.h[0] = half2v{(h16)(wa.x * LOG2E), (h16)(wa.y * LOG2E)};
        wt.h[1] = half2v{(h16)(wa.z * LOG2E), (h16)(wa.w * LOG2E)};
        wt.h[2] = half2v{(h16)(wb.x * LOG2E), (h16)(wb.y * LOG2E)};
        wt.h[3] = half2v{(h16)(wb.z * LOG2E), (h16)(wb.w * LOG2E)};
    }
    const h16 k02 = (h16)0.2f;
    const uint2* XLv = (const uint2*)XL8;  // 8B = 8 fp8 ch; row stride 32 units

    auto ep = [&](const H8& x) -> h16 {
        half2v q{(h16)0, (h16)0};
#pragma unroll
        for (int j = 0; j < 4; ++j) {
            half2v e  = x.h[j] + bv.h[j];
            half2v lr = __builtin_elementwise_max(e, e * k02);
            q += lr * wt.h[j];
        }
        return q.x + q.y;
    };

    float l = 0.f;
    half2v acc[4] = {half2v{(h16)0,(h16)0}, half2v{(h16)0,(h16)0},
                     half2v{(h16)0,(h16)0}, half2v{(h16)0,(h16)0}};

    int4 iv = *(const int4*)(csr_src + start);    // npad >= 4 always
    for (int i = 0; i < npmax; i += 4) {
        int4 cur = iv;
        if (i + 4 < npmax) {
            int nxt = min(i + 4, npad - 4);       // clamp: finished half re-reads
            iv = *(const int4*)(csr_src + start + nxt);
        }
        uint2 v0 = XLv[(size_t)(unsigned)cur.x * 32 + sl];
        uint2 v1 = XLv[(size_t)(unsigned)cur.y * 32 + sl];
        uint2 v2 = XLv[(size_t)(unsigned)cur.z * 32 + sl];
        uint2 v3 = XLv[(size_t)(unsigned)cur.w * 32 + sl];
        H8 x0 = cvt_fp8x8(v0);
        H8 x1 = cvt_fp8x8(v1);
        H8 x2 = cvt_fp8x8(v2);
        H8 x3 = cvt_fp8x8(v3);
        half2v p01 = { ep(x0), ep(x1) };
        half2v p23 = { ep(x2), ep(x3) };
#pragma unroll
        for (int s = 1; s < 8; s <<= 1) {         // 8 lanes per head
            p01 += shfl_xor_h2(p01, s);
            p23 += shfl_xor_h2(p23, s);
        }
        int rem = nreal - i;
        float e0 = (rem > 0) ? exp2f((float)p01.x) : 0.f;
        float e1 = (rem > 1) ? exp2f((float)p01.y) : 0.f;
        float e2 = (rem > 2) ? exp2f((float)p23.x) : 0.f;
        float e3 = (rem > 3) ? exp2f((float)p23.y) : 0.f;
        l += (e0 + e1) + (e2 + e3);
        h16 h0 = (h16)e0, h1 = (h16)e1, h2 = (h16)e2, h3 = (h16)e3;
        half2v eb0{h0,h0}, eb1{h1,h1}, eb2{h2,h2}, eb3{h3,h3};
#pragma unroll
        for (int j = 0; j < 4; ++j) {
            acc[j] += eb0 * x0.h[j];
            acc[j] += eb1 * x1.h[j];
            acc[j] += eb2 * x2.h[j];
            acc[j] += eb3 * x3.h[j];
        }
    }

    float inv = 1.f / l;
    float oc[8];
#pragma unroll
    for (int j = 0; j < 4; ++j) { oc[2*j] = (float)acc[j].x; oc[2*j+1] = (float)acc[j].y; }
    const float4* g4  = (const float4*)gamma;
    const float4* be4 = (const float4*)beta;
    const float4* mu4 = (const float4*)mean;
    const float4* va4 = (const float4*)var;
    const float4* bi4 = (const float4*)bias;
    float o[8];
#pragma unroll
    for (int q = 0; q < 2; ++q) {
        float4 g  = g4[sl*2+q],  bb = be4[sl*2+q], mu = mu4[sl*2+q];
        float4 va = va4[sl*2+q], bi = bi4[sl*2+q];
        float s0 = g.x * rsqrtf(va.x + 1e-5f);
        float s1 = g.y * rsqrtf(va.y + 1e-5f);
        float s2 = g.z * rsqrtf(va.z + 1e-5f);
        float s3 = g.w * rsqrtf(va.w + 1e-5f);
        o[q*4+0] = fmaxf(oc[q*4+0]*inv*s0 + (bi.x-mu.x)*s0 + bb.x, 0.f);
        o[q*4+1] = fmaxf(oc[q*4+1]*inv*s1 + (bi.y-mu.y)*s1 + bb.y, 0.f);
        o[q*4+2] = fmaxf(oc[q*4+2]*inv*s2 + (bi.z-mu.z)*s2 + bb.z, 0.f);
        o[q*4+3] = fmaxf(oc[q*4+3]*inv*s3 + (bi.w-mu.w)*s3 + bb.w, 0.f);
    }
    if (resid) {
        H8 rv; rv.u = *(const uint4*)(resid + (size_t)dr * 256 + sl * 8);
#pragma unroll
        for (int j = 0; j < 4; ++j) {
            o[2*j]   += (float)rv.h[j].x;
            o[2*j+1] += (float)rv.h[j].y;
        }
    }
    if (xl2) {
        // fused layer-2 projection: o[k] = channel sl*8+k of h[dh]
        const float4* wl4 = (const float4*)(Wl2 + sl * 16);
        const float4* wr4 = (const float4*)(Wr2 + sl * 16);
        float l0 = 0.f, l1 = 0.f, r0 = 0.f, r1 = 0.f;
#pragma unroll
        for (int q = 0; q < 4; ++q) {     // float4 q covers channels 2q, 2q+1
            float4 wl = wl4[q];
            float4 wr = wr4[q];
            float oa = o[2*q], ob = o[2*q+1];
            l0 += oa * wl.x + ob * wl.z;
            l1 += oa * wl.y + ob * wl.w;
            r0 += oa * wr.x + ob * wr.z;
            r1 += oa * wr.y + ob * wr.w;
        }
#pragma unroll
        for (int s2 = 1; s2 < 32; s2 <<= 1) {   // reduce within the 32-lane half
            l0 += __shfl_xor(l0, s2, 64);
            l1 += __shfl_xor(l1, s2, 64);
            r0 += __shfl_xor(r0, s2, 64);
            r1 += __shfl_xor(r1, s2, 64);
        }
        if (dvalid && sl == 0) {
            xl2[dh * 2]     = l0;
            xl2[dh * 2 + 1] = l1;
            xr2[dh * 2]     = r0;
            xr2[dh * 2 + 1] = r1;
        }
    } else if (dvalid) {
        H8 ov;
#pragma unroll
        for (int j = 0; j < 4; ++j) ov.h[j] = half2v{(h16)o[2*j], (h16)o[2*j+1]};
        *(uint4*)(outb + (size_t)dh * 256 + sl * 8) = ov.u;
    }
}

// ---- fused layer-2 attention (1 head, C=2) + log_softmax, 16 lanes/dst ----
__global__ void attn1_16(int N, const float* __restrict__ xl2, const float* __restrict__ xr2,
                         const float* __restrict__ att, const float* __restrict__ bias,
                         const int* __restrict__ rowstart, const int* __restrict__ deg,
                         const int* __restrict__ csr_src, float* __restrict__ out) {
    int t = blockIdx.x * blockDim.x + threadIdx.x;
    int d = t >> 4, sl = t & 15;
    if (d >= N) return;
    float a0 = att[0], a1 = att[1];
    float2 xr = ((const float2*)xr2)[d];
    float b0 = xr.x, b1 = xr.y;
    int st = rowstart[d];
    int nreal = deg[d] + 1;
    int npad  = (deg[d] + 4) & ~3;
    float l = 0.f, ac0 = 0.f, ac1 = 0.f;
    for (int i = sl; i < npad; i += 16) {
        int s = csr_src[st + i];
        float2 xv = ((const float2*)xl2)[s];
        float q = lrelu(xv.x + b0) * a0 + lrelu(xv.y + b1) * a1;
        float e = (i < nreal) ? __expf(q) : 0.f;
        l += e; ac0 += e * xv.x; ac1 += e * xv.y;
    }
#pragma unroll
    for (int off = 1; off < 16; off <<= 1) {
        l   += __shfl_xor(l, off, 64);
        ac0 += __shfl_xor(ac0, off, 64);
        ac1 += __shfl_xor(ac1, off, 64);
    }
    if (sl == 0) {
        float inv = 1.f / l;
        float v0 = ac0 * inv + bias[0];
        float v1 = ac1 * inv + bias[1];
        float mx = fmaxf(v0, v1);
        float lse = mx + logf(__expf(v0 - mx) + __expf(v1 - mx));
        out[d * 2] = v0 - lse;
        out[d * 2 + 1] = v1 - lse;
    }
}

extern "C" void kernel_launch(void* const* d_in, const int* in_sizes, int n_in,
                              void* d_out, int out_size, void* d_ws, size_t ws_size,
                              hipStream_t stream) {
    const float* x        = (const float*)d_in[0];
    const int*   ei       = (const int*)  d_in[1];
    const float* W_in     = (const float*)d_in[2];
    const float* b_in     = (const float*)d_in[3];
    const float* Wl0      = (const float*)d_in[4];
    const float* Wr0      = (const float*)d_in[5];
    const float* att0     = (const float*)d_in[6];
    const float* bias0    = (const float*)d_in[7];
    const float* Wl1      = (const float*)d_in[8];
    const float* Wr1      = (const float*)d_in[9];
    const float* att1     = (const float*)d_in[10];
    const float* bias1    = (const float*)d_in[11];
    const float* Wl2      = (const float*)d_in[12];
    const float* Wr2      = (const float*)d_in[13];
    const float* att2     = (const float*)d_in[14];
    const float* bias2    = (const float*)d_in[15];
    const float* bn_gamma = (const float*)d_in[16];
    const float* bn_beta  = (const float*)d_in[17];
    const float* bn_mean  = (const float*)d_in[18];
    const float* bn_var   = (const float*)d_in[19];

    const int N  = in_sizes[0] / 128;
    const int E  = in_sizes[1] / 2;
    const int NB = (N + 255) / 256;

    float* ws = (float*)d_ws;
    size_t off = 0;
    float* XL2  = ws + off; off += (size_t)N * 2;
    float* XR2  = ws + off; off += (size_t)N * 2;
    unsigned char* A8 = (unsigned char*)(ws + off); off += (size_t)N * 64;  // fp8 xl [N,256]
    h16* Bh   = (h16*)(ws + off); off += (size_t)N * 128;  // f16 xr tables [N,256]
    h16* Ch   = (h16*)(ws + off); off += (size_t)N * 128;  // f16 layer0 out / residual
    h16* H0h  = (h16*)(ws + off); off += (size_t)N * 32;   // f16 h0 [N,64]
    h16* xh   = (h16*)(ws + off); off += (size_t)N * 64;   // f16 x  [N,128]
    h16* Wp_in = (h16*)(ws + off); off += 4096;    // 128*64
    h16* Wp_l0 = (h16*)(ws + off); off += 8192;    // 64*256
    h16* Wp_r0 = (h16*)(ws + off); off += 8192;
    h16* Wp_l1 = (h16*)(ws + off); off += 32768;   // 256*256
    h16* Wp_r1 = (h16*)(ws + off); off += 32768;
    int* ip = (int*)(ws + off);
    int* deg      = ip;              ip += N;
    int* rowstart = ip;              ip += N;
    int* cursor   = ip;              ip += N;
    int* bsum     = ip;              ip += NB;
    int* csr_src  = ip;              ip += E + 4 * N + 64;  // padded CSR

    // deg zero
    (void)hipMemsetAsync(deg, 0, (size_t)N * sizeof(int), stream);

    // ---- weight packing + x conversion + dst histogram (one launch) ----
    const int PACK_T = 172032 + N * 32 + E;
    pack_all<<<(PACK_T + 255) / 256, 256, 0, stream>>>(
        W_in, Wl0, Wr0, Wl1, Wr1, Wp_in, Wp_l0, Wp_r0, Wp_l1, Wp_r1,
        (const float4*)x, (half4v*)xh, N * 32, ei, E, deg);

    // ---- CSR build (parallel scan, padded rows incl. self-loop) ----
    scan_blk<<<NB, 256, 0, stream>>>(deg, rowstart, bsum, N);
    scan_off<<<1, 256, 0, stream>>>(bsum, NB);
    add_off<<<NB, 256, 0, stream>>>(bsum, deg, rowstart, cursor, csr_src, N);

    const int GBM = (N + 63) / 64;
    const int E2  = ((E / 2) + 4095) & ~4095;          // first-half edge count
    const int GS0 = E2 / 4096;                          // blocks for half 1
    const int GS1 = (E - E2 + 4095) / 4096;             // blocks for half 2

    // scatter half-1  ||  h0 = relu(x @ W_in + b_in) -> f16
    scatter_gemm0<<<GS0 + GBM, 256, 0, stream>>>(ei, E2, E, cursor, csr_src, GS0,
                                                 xh, Wp_in, b_in, H0h, N);

    // scatter half-2  ||  layer-0 dual GEMM (xl->fp8 A8, xr->f16 Bh)
    scatter_gemmL0<<<GS1 + 2 * GBM, 256, 0, stream>>>(ei, E2, E, cursor, csr_src,
                                                      GS1, GBM, H0h, Wp_l0, Wp_r0,
                                                      A8, Bh, N);

    // -------- layer 0 attention --------
    attn4_bn<<<(N + 7) / 8, 256, 0, stream>>>(N, A8, Bh, att0,
                                              rowstart, deg, csr_src,
                                              bn_gamma, bn_beta, bn_mean, bn_var,
                                              bias0, nullptr, Ch,
                                              nullptr, nullptr, nullptr, nullptr);

    // -------- layer 1 (residual) + fused layer-2 projection --------
    gemm_lds<8, 16, false, true, true><<<dim3(GBM, 2), 256, 0, stream>>>(
        Ch, Wp_l1, Wp_r1, nullptr, A8, Bh, N);
    attn4_bn<<<(N + 7) / 8, 256, 0, stream>>>(N, A8, Bh, att1,
                                              rowstart, deg, csr_src,
                                              bn_gamma + 256, bn_beta + 256, bn_mean + 256,
                                              bn_var + 256, bias1, Ch, nullptr,
                                              Wl2, Wr2, XL2, XR2);

    // -------- layer 2 (1 head, C=2) + log_softmax --------
    attn1_16<<<(N * 16 + 255) / 256, 256, 0, stream>>>(N, XL2, XR2, att2, bias2,
                                                       rowstart, deg, csr_src, (float*)d_out);
}

// Round 20
// 368.566 us; speedup vs baseline: 1.0930x; 1.0036x over previous
//
#include <hip/hip_runtime.h>
#include <hip/hip_bf16.h>
#include <math.h>

// ---------------------------------------------------------------------------
// GATv2 3-layer GNN. CSR-by-dst padded to 4-edge batches (self-loop folded
// in); f16 MFMA GEMMs; BN/ReLU/residual fused into attention; layer-2
// projection fused into layer-1 attention epilogue.
// R19 measured: 369.9us. 16-chain scatter gain small (-3.7us) -> scatter at
// floor under co-launched GEMMs. Post-scatter chain inherently serial.
// R19 change: delete the scan_off launch — each add_off block reduces
// bsum[0..j-1] itself (<=196 ints, wave+LDS reduce). One launch + one
// dependency hop removed; CSR semantics unchanged.
// ---------------------------------------------------------------------------

using h16     = _Float16;
using half2v  = __attribute__((ext_vector_type(2))) h16;
using half4v  = __attribute__((ext_vector_type(4))) h16;
using half8   = __attribute__((ext_vector_type(8))) h16;
using floatx2 = __attribute__((ext_vector_type(2))) float;
using floatx4 = __attribute__((ext_vector_type(4))) float;

__device__ __forceinline__ float lrelu(float x) { return x > 0.f ? x : 0.2f * x; }

__device__ __forceinline__ half2v shfl_xor_h2(half2v v, int mask) {
    float f = __builtin_bit_cast(float, v);
    f = __shfl_xor(f, mask, 64);
    return __builtin_bit_cast(half2v, f);
}

union H8 { uint4 u; half2v h[4]; };

// 4 fp8 (one dword) -> half4 via HW cvt
__device__ __forceinline__ half4v cvt_fp8x4(unsigned v) {
    floatx2 lo = __builtin_amdgcn_cvt_pk_f32_fp8((int)v, false);
    floatx2 hi = __builtin_amdgcn_cvt_pk_f32_fp8((int)v, true);
    half4v r = { (h16)lo.x, (h16)lo.y, (h16)hi.x, (h16)hi.y };
    return r;
}

// 8 fp8 (uint2) -> H8 (8 f16 channels)
__device__ __forceinline__ H8 cvt_fp8x8(uint2 v) {
    half4v a = cvt_fp8x4(v.x);
    half4v b = cvt_fp8x4(v.y);
    H8 r;
    r.h[0] = a.xy; r.h[1] = a.zw;
    r.h[2] = b.xy; r.h[3] = b.zw;
    return r;
}

// ---------------- CSR build ----------------
// padded row length = ceil((deg+1)/4)*4  (self-loop + pads)
// scan_blk: intra-block exclusive prefix -> rowstart; raw block total -> bsum
__global__ __launch_bounds__(256) void scan_blk(const int* __restrict__ deg,
                                                int* __restrict__ rowstart,
                                                int* __restrict__ bsum, int N) {
    int t = blockIdx.x * 256 + threadIdx.x;
    int lane = threadIdx.x & 63, wid = threadIdx.x >> 6;
    int v = (t < N) ? ((deg[t] + 4) & ~3) : 0;
    int x = v;
#pragma unroll
    for (int off = 1; off < 64; off <<= 1) {
        int y = __shfl_up(x, off, 64);
        if (lane >= off) x += y;
    }
    __shared__ int wsum[4];
    if (lane == 63) wsum[wid] = x;
    __syncthreads();
    int add = 0;
#pragma unroll
    for (int w = 0; w < 4; ++w) if (w < wid) add += wsum[w];
    int incl = x + add;
    if (t < N) rowstart[t] = incl - v;
    if (threadIdx.x == 255) bsum[blockIdx.x] = incl;
}

// add_off: block j reduces bsum[0..j-1] itself (scan_off fused away).
__global__ __launch_bounds__(256) void add_off(
        const int* __restrict__ bsum, const int* __restrict__ deg,
        int* __restrict__ rowstart, int* __restrict__ cursor,
        int* __restrict__ csr_src, int N, int NB) {
    // ---- block base = sum of preceding block totals ----
    int lane = threadIdx.x & 63, wid = threadIdx.x >> 6;
    int val = 0;
    for (int i = threadIdx.x; i < (int)blockIdx.x; i += 256) val += bsum[i];
#pragma unroll
    for (int off = 1; off < 64; off <<= 1) val += __shfl_xor(val, off, 64);
    __shared__ int rbuf[4];
    if (lane == 0) rbuf[wid] = val;
    __syncthreads();
    int base = rbuf[0] + rbuf[1] + rbuf[2] + rbuf[3];

    int t = blockIdx.x * 256 + threadIdx.x;
    if (t >= N) return;
    int r = rowstart[t] + base;
    rowstart[t] = r;
    cursor[t] = r;
    int dg = deg[t];
    int npad = (dg + 4) & ~3;
    for (int k = dg; k < npad; ++k) csr_src[r + k] = t;
}

// ------- weight packing + x conversion + dst histogram (one launch) -------
__device__ __forceinline__ void pack_one(const float* __restrict__ W,
                                         h16* __restrict__ Wp,
                                         int t, int K, int NC) {
    int j = t & 7;
    int l = (t >> 3) & 63;
    int rest = t >> 9;
    int NT = NC >> 4;
    int nt = rest % NT;
    int kc = rest / NT;
    int row = kc * 32 + (l >> 4) * 8 + j;
    int col = nt * 16 + (l & 15);
    Wp[t] = (h16)W[(size_t)row * NC + col];
}

__global__ void pack_all(const float* __restrict__ W_in,
                         const float* __restrict__ Wl0, const float* __restrict__ Wr0,
                         const float* __restrict__ Wl1, const float* __restrict__ Wr1,
                         h16* __restrict__ P_in,
                         h16* __restrict__ P_l0, h16* __restrict__ P_r0,
                         h16* __restrict__ P_l1, h16* __restrict__ P_r1,
                         const float4* __restrict__ x, half4v* __restrict__ xh, int n4,
                         const int* __restrict__ ei, int E, int* __restrict__ deg) {
    int t = blockIdx.x * blockDim.x + threadIdx.x;
    if (t < 8192)        pack_one(W_in, P_in, t, 128, 64);
    else if (t < 24576)  pack_one(Wl0, P_l0, t - 8192, 64, 256);
    else if (t < 40960)  pack_one(Wr0, P_r0, t - 24576, 64, 256);
    else if (t < 106496) pack_one(Wl1, P_l1, t - 40960, 256, 256);
    else if (t < 172032) pack_one(Wr1, P_r1, t - 106496, 256, 256);
    else if (t < 172032 + n4) {
        int u = t - 172032;
        float4 v = x[u];
        half4v o = { (h16)v.x, (h16)v.y, (h16)v.z, (h16)v.w };
        xh[u] = o;
    } else {
        int u = t - 172032 - n4;
        if (u < E) atomicAdd(&deg[ei[E + u]], 1);   // no-return atomic: throughput-ok
    }
}

// --------- MFMA GEMM body, double-buffered LDS staging of W ----------------
// OUT8: write fp8 e4m3 instead of f16 (attention XL table).
template<int KC, int NT, bool RELU, bool OUT8>
__device__ __forceinline__ void gemm_body(const h16* __restrict__ Xh,
                                          const h16* __restrict__ Wp,
                                          const float* __restrict__ bias,
                                          void* __restrict__ outp, int M, int bx) {
    constexpr int K = KC * 32;
    constexpr int ldo = NT * 16;
    constexpr int CHUNK8 = NT * 64;
    constexpr int PER_THR = CHUNK8 / 256;
    __shared__ half8 wbuf[2][CHUNK8];

    const half8* WG = (const half8*)Wp;
    const int tid = threadIdx.x;
    const int wid = tid >> 6, lane = tid & 63;
    const int quad = lane >> 4, li = lane & 15;
    const int r0 = bx * 64 + wid * 16;
    int arow = r0 + li; if (arow >= M) arow = M - 1;
    const half8* A8 = (const half8*)Xh + (size_t)arow * (K / 8) + quad;

    floatx4 acc[NT];
#pragma unroll
    for (int t = 0; t < NT; ++t) acc[t] = (floatx4){0.f, 0.f, 0.f, 0.f};

    half8 st[PER_THR];
#pragma unroll
    for (int i = 0; i < PER_THR; ++i) st[i] = WG[i * 256 + tid];
#pragma unroll
    for (int i = 0; i < PER_THR; ++i) wbuf[0][i * 256 + tid] = st[i];
    __syncthreads();

#pragma unroll
    for (int kc = 0; kc < KC; ++kc) {
        int cur = kc & 1;
        if (kc + 1 < KC) {
#pragma unroll
            for (int i = 0; i < PER_THR; ++i)
                st[i] = WG[(size_t)(kc + 1) * CHUNK8 + i * 256 + tid];
        }
        half8 a = A8[kc * 4];
#pragma unroll
        for (int nt = 0; nt < NT; ++nt) {
            half8 b = wbuf[cur][nt * 64 + lane];
            acc[nt] = __builtin_amdgcn_mfma_f32_16x16x32_f16(a, b, acc[nt], 0, 0, 0);
        }
        if (kc + 1 < KC) {
#pragma unroll
            for (int i = 0; i < PER_THR; ++i) wbuf[cur ^ 1][i * 256 + tid] = st[i];
        }
        __syncthreads();
    }

#pragma unroll
    for (int nt = 0; nt < NT; ++nt) {
#pragma unroll
        for (int reg = 0; reg < 4; ++reg) {
            int rr = r0 + quad * 4 + reg;
            if (rr >= M) continue;
            float v = acc[nt][reg];
            if (RELU) v = fmaxf(v + bias[nt * 16 + li], 0.f);
            if (OUT8) {
                int pk = __builtin_amdgcn_cvt_pk_fp8_f32(v, v, 0, false);
                ((unsigned char*)outp)[(size_t)rr * ldo + nt * 16 + li] = (unsigned char)pk;
            } else {
                ((h16*)outp)[(size_t)rr * ldo + nt * 16 + li] = (h16)v;
            }
        }
    }
}

// DUAL grid.y: y==0 -> out0 (fp8 if OUT8L), y==1 -> out1 (f16)
template<int KC, int NT, bool RELU, bool DUAL, bool OUT8L>
__global__ __launch_bounds__(256) void gemm_lds(
        const h16* __restrict__ Xh,
        const h16* __restrict__ Wp0, const h16* __restrict__ Wp1,
        const float* __restrict__ bias,
        void* __restrict__ out0, void* __restrict__ out1, int M) {
    if (DUAL && blockIdx.y) {
        gemm_body<KC, NT, RELU, false>(Xh, Wp1, bias, out1, M, blockIdx.x);
    } else {
        gemm_body<KC, NT, RELU, OUT8L>(Xh, Wp0, bias, out0, M, blockIdx.x);
    }
}

// ---- edge scatter helper: 16 edges/thread, independent atomic chains -----
// E    = true edge count (dst row of ei lives at ei+E)   -- offset role
// elim = exclusive upper bound of the edge range handled -- bound role
__device__ __forceinline__ void scatter16(const int* __restrict__ ei, int E, int elim,
                                          int ebase, int* __restrict__ cursor,
                                          int* __restrict__ csr_src, int bx) {
    int base = ebase + bx * 4096 + threadIdx.x;
    int e[16], d[16], p[16], s[16];
#pragma unroll
    for (int k = 0; k < 16; ++k) e[k] = base + k * 256;
#pragma unroll
    for (int k = 0; k < 16; ++k) d[k] = (e[k] < elim) ? ei[E + e[k]] : 0;
#pragma unroll
    for (int k = 0; k < 16; ++k) p[k] = (e[k] < elim) ? atomicAdd(&cursor[d[k]], 1) : 0;
#pragma unroll
    for (int k = 0; k < 16; ++k) s[k] = (e[k] < elim) ? ei[e[k]] : 0;
#pragma unroll
    for (int k = 0; k < 16; ++k) if (e[k] < elim) csr_src[p[k]] = s[k];
}

// ---- scatter (first half of edges) || h0 GEMM ----------------------------
__global__ __launch_bounds__(256) void scatter_gemm0(
        const int* __restrict__ ei, int E2, int E,
        int* __restrict__ cursor, int* __restrict__ csr_src, int GS,
        const h16* __restrict__ xh, const h16* __restrict__ Wp_in,
        const float* __restrict__ b_in, h16* __restrict__ H0h, int M) {
    if ((int)blockIdx.x < GS) {
        scatter16(ei, E, E2 < E ? E2 : E, 0, cursor, csr_src, blockIdx.x);
    } else {
        gemm_body<4, 4, true, false>(xh, Wp_in, b_in, H0h, M, blockIdx.x - GS);
    }
}

// ---- scatter (second half of edges) || layer-0 dual GEMM -----------------
__global__ __launch_bounds__(256) void scatter_gemmL0(
        const int* __restrict__ ei, int E2, int E,
        int* __restrict__ cursor, int* __restrict__ csr_src, int GS, int GBM,
        const h16* __restrict__ H0h,
        const h16* __restrict__ Wp_l0, const h16* __restrict__ Wp_r0,
        unsigned char* __restrict__ A8, h16* __restrict__ Bh, int M) {
    if ((int)blockIdx.x < GS) {
        scatter16(ei, E, E, E2, cursor, csr_src, blockIdx.x);
    } else if ((int)blockIdx.x < GS + GBM) {
        gemm_body<2, 16, false, true>(H0h, Wp_l0, nullptr, A8, M, blockIdx.x - GS);
    } else {
        gemm_body<2, 16, false, false>(H0h, Wp_r0, nullptr, Bh, M, blockIdx.x - GS - GBM);
    }
}

// ---- fused 4-head attention + BN + ReLU (+residual) (+proj), 2 dst/wave --
// XL table fp8 (gathered side, HW cvt on read); XR/resid/out f16.
// 32 lanes per dst, 8 channels per lane. Head = 8 lanes -> 3-stage shfl.
// If xl2 != nullptr (layer 1): project h @ Wl2 / Wr2 (256->2 each)
// in-register and write only xl2/xr2 (f32 [N][2]) -- gemm2_wave fused away.
__global__ __launch_bounds__(256) void attn4_bn(
                         int N, const unsigned char* __restrict__ XL8,
                         const h16* __restrict__ XR,
                         const float* __restrict__ att,
                         const int* __restrict__ rowstart, const int* __restrict__ deg,
                         const int* __restrict__ csr_src,
                         const float* __restrict__ gamma, const float* __restrict__ beta,
                         const float* __restrict__ mean, const float* __restrict__ var,
                         const float* __restrict__ bias, const h16* __restrict__ resid,
                         h16* __restrict__ outb,
                         const float* __restrict__ Wl2, const float* __restrict__ Wr2,
                         float* __restrict__ xl2, float* __restrict__ xr2) {
    int wv = blockIdx.x * (blockDim.x >> 6) + (threadIdx.x >> 6);
    int d0 = wv * 2;
    if (d0 >= N) return;
    int lane = threadIdx.x & 63;
    int sl   = lane & 31;                 // lane within the 32-lane half
    int dh   = d0 + (lane >> 5);          // this half's dst
    bool dvalid = dh < N;
    int dr = dvalid ? dh : d0;

    int start = rowstart[dr];
    int dg    = deg[dr];
    int nreal = dg + 1;                   // self-loop included in CSR
    int npad  = (dg + 4) & ~3;            // row padded to multiple of 4
    int npmax = max(npad, __shfl_xor(npad, 32, 64));

    H8 bv, wt;
    bv.u = *(const uint4*)(XR + (size_t)dr * 256 + sl * 8);
    {
        const float LOG2E = 1.44269504088896340736f;   // folded into logits
        const float* ar = att + (sl >> 3) * 64 + (sl & 7) * 8;
        float4 wa = *(const float4*)ar;
        float4 wb = *(const float4*)(ar + 4);
        wt.h[0] = half2v{(h16)(wa.x * LOG2E), (h16)(wa.y * LOG2E)};
        wt.h[1] = half2v{(h16)(wa.z * LOG2E), (h16)(wa.w * LOG2E)};
        wt.h[2] = half2v{(h16)(wb.x * LOG2E), (h16)(wb.y * LOG2E)};
        wt.h[3] = half2v{(h16)(wb.z * LOG2E), (h16)(wb.w * LOG2E)};
    }
    const h16 k02 = (h16)0.2f;
    const uint2* XLv = (const uint2*)XL8;  // 8B = 8 fp8 ch; row stride 32 units

    auto ep = [&](const H8& x) -> h16 {
        half2v q{(h16)0, (h16)0};
#pragma unroll
        for (int j = 0; j < 4; ++j) {
            half2v e  = x.h[j] + bv.h[j];
            half2v lr = __builtin_elementwise_max(e, e * k02);
            q += lr * wt.h[j];
        }
        return q.x + q.y;
    };

    float l = 0.f;
    half2v acc[4] = {half2v{(h16)0,(h16)0}, half2v{(h16)0,(h16)0},
                     half2v{(h16)0,(h16)0}, half2v{(h16)0,(h16)0}};

    int4 iv = *(const int4*)(csr_src + start);    // npad >= 4 always
    for (int i = 0; i < npmax; i += 4) {
        int4 cur = iv;
        if (i + 4 < npmax) {
            int nxt = min(i + 4, npad - 4);       // clamp: finished half re-reads
            iv = *(const int4*)(csr_src + start + nxt);
        }
        uint2 v0 = XLv[(size_t)(unsigned)cur.x * 32 + sl];
        uint2 v1 = XLv[(size_t)(unsigned)cur.y * 32 + sl];
        uint2 v2 = XLv[(size_t)(unsigned)cur.z * 32 + sl];
        uint2 v3 = XLv[(size_t)(unsigned)cur.w * 32 + sl];
        H8 x0 = cvt_fp8x8(v0);
        H8 x1 = cvt_fp8x8(v1);
        H8 x2 = cvt_fp8x8(v2);
        H8 x3 = cvt_fp8x8(v3);
        half2v p01 = { ep(x0), ep(x1) };
        half2v p23 = { ep(x2), ep(x3) };
#pragma unroll
        for (int s = 1; s < 8; s <<= 1) {         // 8 lanes per head
            p01 += shfl_xor_h2(p01, s);
            p23 += shfl_xor_h2(p23, s);
        }
        int rem = nreal - i;
        float e0 = (rem > 0) ? exp2f((float)p01.x) : 0.f;
        float e1 = (rem > 1) ? exp2f((float)p01.y) : 0.f;
        float e2 = (rem > 2) ? exp2f((float)p23.x) : 0.f;
        float e3 = (rem > 3) ? exp2f((float)p23.y) : 0.f;
        l += (e0 + e1) + (e2 + e3);
        h16 h0 = (h16)e0, h1 = (h16)e1, h2 = (h16)e2, h3 = (h16)e3;
        half2v eb0{h0,h0}, eb1{h1,h1}, eb2{h2,h2}, eb3{h3,h3};
#pragma unroll
        for (int j = 0; j < 4; ++j) {
            acc[j] += eb0 * x0.h[j];
            acc[j] += eb1 * x1.h[j];
            acc[j] += eb2 * x2.h[j];
            acc[j] += eb3 * x3.h[j];
        }
    }

    float inv = 1.f / l;
    float oc[8];
#pragma unroll
    for (int j = 0; j < 4; ++j) { oc[2*j] = (float)acc[j].x; oc[2*j+1] = (float)acc[j].y; }
    const float4* g4  = (const float4*)gamma;
    const float4* be4 = (const float4*)beta;
    const float4* mu4 = (const float4*)mean;
    const float4* va4 = (const float4*)var;
    const float4* bi4 = (const float4*)bias;
    float o[8];
#pragma unroll
    for (int q = 0; q < 2; ++q) {
        float4 g  = g4[sl*2+q],  bb = be4[sl*2+q], mu = mu4[sl*2+q];
        float4 va = va4[sl*2+q], bi = bi4[sl*2+q];
        float s0 = g.x * rsqrtf(va.x + 1e-5f);
        float s1 = g.y * rsqrtf(va.y + 1e-5f);
        float s2 = g.z * rsqrtf(va.z + 1e-5f);
        float s3 = g.w * rsqrtf(va.w + 1e-5f);
        o[q*4+0] = fmaxf(oc[q*4+0]*inv*s0 + (bi.x-mu.x)*s0 + bb.x, 0.f);
        o[q*4+1] = fmaxf(oc[q*4+1]*inv*s1 + (bi.y-mu.y)*s1 + bb.y, 0.f);
        o[q*4+2] = fmaxf(oc[q*4+2]*inv*s2 + (bi.z-mu.z)*s2 + bb.z, 0.f);
        o[q*4+3] = fmaxf(oc[q*4+3]*inv*s3 + (bi.w-mu.w)*s3 + bb.w, 0.f);
    }
    if (resid) {
        H8 rv; rv.u = *(const uint4*)(resid + (size_t)dr * 256 + sl * 8);
#pragma unroll
        for (int j = 0; j < 4; ++j) {
            o[2*j]   += (float)rv.h[j].x;
            o[2*j+1] += (float)rv.h[j].y;
        }
    }
    if (xl2) {
        // fused layer-2 projection: o[k] = channel sl*8+k of h[dh]
        const float4* wl4 = (const float4*)(Wl2 + sl * 16);
        const float4* wr4 = (const float4*)(Wr2 + sl * 16);
        float l0 = 0.f, l1 = 0.f, r0 = 0.f, r1 = 0.f;
#pragma unroll
        for (int q = 0; q < 4; ++q) {     // float4 q covers channels 2q, 2q+1
            float4 wl = wl4[q];
            float4 wr = wr4[q];
            float oa = o[2*q], ob = o[2*q+1];
            l0 += oa * wl.x + ob * wl.z;
            l1 += oa * wl.y + ob * wl.w;
            r0 += oa * wr.x + ob * wr.z;
            r1 += oa * wr.y + ob * wr.w;
        }
#pragma unroll
        for (int s2 = 1; s2 < 32; s2 <<= 1) {   // reduce within the 32-lane half
            l0 += __shfl_xor(l0, s2, 64);
            l1 += __shfl_xor(l1, s2, 64);
            r0 += __shfl_xor(r0, s2, 64);
            r1 += __shfl_xor(r1, s2, 64);
        }
        if (dvalid && sl == 0) {
            xl2[dh * 2]     = l0;
            xl2[dh * 2 + 1] = l1;
            xr2[dh * 2]     = r0;
            xr2[dh * 2 + 1] = r1;
        }
    } else if (dvalid) {
        H8 ov;
#pragma unroll
        for (int j = 0; j < 4; ++j) ov.h[j] = half2v{(h16)o[2*j], (h16)o[2*j+1]};
        *(uint4*)(outb + (size_t)dh * 256 + sl * 8) = ov.u;
    }
}

// ---- fused layer-2 attention (1 head, C=2) + log_softmax, 16 lanes/dst ----
__global__ void attn1_16(int N, const float* __restrict__ xl2, const float* __restrict__ xr2,
                         const float* __restrict__ att, const float* __restrict__ bias,
                         const int* __restrict__ rowstart, const int* __restrict__ deg,
                         const int* __restrict__ csr_src, float* __restrict__ out) {
    int t = blockIdx.x * blockDim.x + threadIdx.x;
    int d = t >> 4, sl = t & 15;
    if (d >= N) return;
    float a0 = att[0], a1 = att[1];
    float2 xr = ((const float2*)xr2)[d];
    float b0 = xr.x, b1 = xr.y;
    int st = rowstart[d];
    int nreal = deg[d] + 1;
    int npad  = (deg[d] + 4) & ~3;
    float l = 0.f, ac0 = 0.f, ac1 = 0.f;
    for (int i = sl; i < npad; i += 16) {
        int s = csr_src[st + i];
        float2 xv = ((const float2*)xl2)[s];
        float q = lrelu(xv.x + b0) * a0 + lrelu(xv.y + b1) * a1;
        float e = (i < nreal) ? __expf(q) : 0.f;
        l += e; ac0 += e * xv.x; ac1 += e * xv.y;
    }
#pragma unroll
    for (int off = 1; off < 16; off <<= 1) {
        l   += __shfl_xor(l, off, 64);
        ac0 += __shfl_xor(ac0, off, 64);
        ac1 += __shfl_xor(ac1, off, 64);
    }
    if (sl == 0) {
        float inv = 1.f / l;
        float v0 = ac0 * inv + bias[0];
        float v1 = ac1 * inv + bias[1];
        float mx = fmaxf(v0, v1);
        float lse = mx + logf(__expf(v0 - mx) + __expf(v1 - mx));
        out[d * 2] = v0 - lse;
        out[d * 2 + 1] = v1 - lse;
    }
}

extern "C" void kernel_launch(void* const* d_in, const int* in_sizes, int n_in,
                              void* d_out, int out_size, void* d_ws, size_t ws_size,
                              hipStream_t stream) {
    const float* x        = (const float*)d_in[0];
    const int*   ei       = (const int*)  d_in[1];
    const float* W_in     = (const float*)d_in[2];
    const float* b_in     = (const float*)d_in[3];
    const float* Wl0      = (const float*)d_in[4];
    const float* Wr0      = (const float*)d_in[5];
    const float* att0     = (const float*)d_in[6];
    const float* bias0    = (const float*)d_in[7];
    const float* Wl1      = (const float*)d_in[8];
    const float* Wr1      = (const float*)d_in[9];
    const float* att1     = (const float*)d_in[10];
    const float* bias1    = (const float*)d_in[11];
    const float* Wl2      = (const float*)d_in[12];
    const float* Wr2      = (const float*)d_in[13];
    const float* att2     = (const float*)d_in[14];
    const float* bias2    = (const float*)d_in[15];
    const float* bn_gamma = (const float*)d_in[16];
    const float* bn_beta  = (const float*)d_in[17];
    const float* bn_mean  = (const float*)d_in[18];
    const float* bn_var   = (const float*)d_in[19];

    const int N  = in_sizes[0] / 128;
    const int E  = in_sizes[1] / 2;
    const int NB = (N + 255) / 256;

    float* ws = (float*)d_ws;
    size_t off = 0;
    float* XL2  = ws + off; off += (size_t)N * 2;
    float* XR2  = ws + off; off += (size_t)N * 2;
    unsigned char* A8 = (unsigned char*)(ws + off); off += (size_t)N * 64;  // fp8 xl [N,256]
    h16* Bh   = (h16*)(ws + off); off += (size_t)N * 128;  // f16 xr tables [N,256]
    h16* Ch   = (h16*)(ws + off); off += (size_t)N * 128;  // f16 layer0 out / residual
    h16* H0h  = (h16*)(ws + off); off += (size_t)N * 32;   // f16 h0 [N,64]
    h16* xh   = (h16*)(ws + off); off += (size_t)N * 64;   // f16 x  [N,128]
    h16* Wp_in = (h16*)(ws + off); off += 4096;    // 128*64
    h16* Wp_l0 = (h16*)(ws + off); off += 8192;    // 64*256
    h16* Wp_r0 = (h16*)(ws + off); off += 8192;
    h16* Wp_l1 = (h16*)(ws + off); off += 32768;   // 256*256
    h16* Wp_r1 = (h16*)(ws + off); off += 32768;
    int* ip = (int*)(ws + off);
    int* deg      = ip;              ip += N;
    int* rowstart = ip;              ip += N;
    int* cursor   = ip;              ip += N;
    int* bsum     = ip;              ip += NB;
    int* csr_src  = ip;              ip += E + 4 * N + 64;  // padded CSR

    // deg zero
    (void)hipMemsetAsync(deg, 0, (size_t)N * sizeof(int), stream);

    // ---- weight packing + x conversion + dst histogram (one launch) ----
    const int PACK_T = 172032 + N * 32 + E;
    pack_all<<<(PACK_T + 255) / 256, 256, 0, stream>>>(
        W_in, Wl0, Wr0, Wl1, Wr1, Wp_in, Wp_l0, Wp_r0, Wp_l1, Wp_r1,
        (const float4*)x, (half4v*)xh, N * 32, ei, E, deg);

    // ---- CSR build (block scan + fused base-reduce; scan_off removed) ----
    scan_blk<<<NB, 256, 0, stream>>>(deg, rowstart, bsum, N);
    add_off<<<NB, 256, 0, stream>>>(bsum, deg, rowstart, cursor, csr_src, N, NB);

    const int GBM = (N + 63) / 64;
    const int E2  = ((E / 2) + 4095) & ~4095;          // first-half edge count
    const int GS0 = E2 / 4096;                          // blocks for half 1
    const int GS1 = (E - E2 + 4095) / 4096;             // blocks for half 2

    // scatter half-1  ||  h0 = relu(x @ W_in + b_in) -> f16
    scatter_gemm0<<<GS0 + GBM, 256, 0, stream>>>(ei, E2, E, cursor, csr_src, GS0,
                                                 xh, Wp_in, b_in, H0h, N);

    // scatter half-2  ||  layer-0 dual GEMM (xl->fp8 A8, xr->f16 Bh)
    scatter_gemmL0<<<GS1 + 2 * GBM, 256, 0, stream>>>(ei, E2, E, cursor, csr_src,
                                                      GS1, GBM, H0h, Wp_l0, Wp_r0,
                                                      A8, Bh, N);

    // -------- layer 0 attention --------
    attn4_bn<<<(N + 7) / 8, 256, 0, stream>>>(N, A8, Bh, att0,
                                              rowstart, deg, csr_src,
                                              bn_gamma, bn_beta, bn_mean, bn_var,
                                              bias0, nullptr, Ch,
                                              nullptr, nullptr, nullptr, nullptr);

    // -------- layer 1 (residual) + fused layer-2 projection --------
    gemm_lds<8, 16, false, true, true><<<dim3(GBM, 2), 256, 0, stream>>>(
        Ch, Wp_l1, Wp_r1, nullptr, A8, Bh, N);
    attn4_bn<<<(N + 7) / 8, 256, 0, stream>>>(N, A8, Bh, att1,
                                              rowstart, deg, csr_src,
                                              bn_gamma + 256, bn_beta + 256, bn_mean + 256,
                                              bn_var + 256, bias1, Ch, nullptr,
                                              Wl2, Wr2, XL2, XR2);

    // -------- layer 2 (1 head, C=2) + log_softmax --------
    attn1_16<<<(N * 16 + 255) / 256, 256, 0, stream>>>(N, XL2, XR2, att2, bias2,
                                                       rowstart, deg, csr_src, (float*)d_out);
}